// Round 15
// baseline (766.077 us; speedup 1.0000x reference)
//
#include <hip/hip_runtime.h>
#include <hip/hip_bf16.h>
#include <math.h>

// ---- problem constants ----
#define T_TOK  4096      // B*S tokens
#define H_DIM  1024
#define E_NUM  8
#define FF_DIM 4096
#define KSEL   2
#define SLOTS  (T_TOK*KSEL)     // 8192
#define SLOTS_PAD (SLOTS + 256)
#define BM 128
#define MAXTILES 72             // 128-row tiles (18 bands of 4)

typedef __attribute__((ext_vector_type(8))) short s16x8;
typedef __attribute__((ext_vector_type(8))) unsigned short u16x8;
typedef __attribute__((ext_vector_type(4))) float f32x4;

typedef __attribute__((address_space(1))) const void global_cvoid;
typedef __attribute__((address_space(3))) void lds_void;

__device__ __forceinline__ unsigned short f2bf(float f){
  unsigned int u = __float_as_uint(f);
  u += 0x7fffu + ((u>>16)&1u);
  return (unsigned short)(u>>16);
}
__device__ __forceinline__ float bf2f(unsigned short h){
  return __uint_as_float(((unsigned int)h)<<16);
}

// ---- workspace layout ----
static constexpr size_t OFF_CNT   = 0;
static constexpr size_t OFF_OFFS  = 256;
static constexpr size_t OFF_NT    = 512;
static constexpr size_t OFF_TILES = 768;
static constexpr size_t OFF_IDX   = 1280;
static constexpr size_t OFF_POS   = OFF_IDX  + 32768;
static constexpr size_t OFF_WV    = OFF_POS  + 32768;
static constexpr size_t OFF_SLOT  = OFF_WV   + 32768;   // [T][2] int
static constexpr size_t OFF_TOK   = OFF_SLOT + 32768;   // [SLOTS] int
static constexpr size_t OFF_WOF   = OFF_TOK  + 32768;   // [SLOTS] float
static constexpr size_t OFF_XG    = OFF_WOF  + 32768;                       // [SLOTS_PAD][H] bf16
static constexpr size_t OFF_W1T   = OFF_XG  + (size_t)SLOTS_PAD*H_DIM*2;    // [E][FF][H] bf16
static constexpr size_t OFF_W2T   = OFF_W1T + (size_t)E_NUM*H_DIM*FF_DIM*2; // [E][H][FF] bf16
static constexpr size_t OFF_MID   = OFF_W2T + (size_t)E_NUM*H_DIM*FF_DIM*2; // [SLOTS_PAD][FF] bf16
static constexpr size_t OFF_Y     = OFF_MID + (size_t)SLOTS_PAD*FF_DIM*2;   // [SLOTS][H] bf16

// ---- gating: 4 tokens per block (validated r10) ----
__global__ __launch_bounds__(64) void gate_kernel(
    const float* __restrict__ x, const float* __restrict__ Wg,
    const float* __restrict__ bg, int* __restrict__ cnt,
    int* __restrict__ idxp, int* __restrict__ posp, float* __restrict__ wvp)
{
  int lane = threadIdx.x;
  for (int tt=0; tt<4; ++tt){
    int t = blockIdx.x*4 + tt;
    const float* xr = x + (size_t)t*H_DIM;
    float acc[E_NUM];
    #pragma unroll
    for (int e=0;e<E_NUM;e++) acc[e]=0.f;
    for (int i=0;i<H_DIM/64;i++){
      int h = i*64 + lane;
      float xv = xr[h];
      const float* wr_ = Wg + (size_t)h*E_NUM;
      #pragma unroll
      for (int e=0;e<E_NUM;e++) acc[e] += xv*wr_[e];
    }
    #pragma unroll
    for (int e=0;e<E_NUM;e++){
      #pragma unroll
      for (int off=32; off>0; off>>=1) acc[e] += __shfl_xor(acc[e], off);
    }
    if (lane==0){
      float l[E_NUM];
      #pragma unroll
      for (int e=0;e<E_NUM;e++) l[e] = acc[e] + bg[e];
      int i0 = 0;
      #pragma unroll
      for (int e=1;e<E_NUM;e++) if (l[e] > l[i0]) i0 = e;
      int i1 = (i0==0)?1:0;
      #pragma unroll
      for (int e=0;e<E_NUM;e++) if (e!=i0 && l[e] > l[i1]) i1 = e;
      float p1 = expf(l[i1]-l[i0]);
      float s  = 1.f + p1;
      float w0 = 1.f/s, w1 = p1/s;
      int pos0 = atomicAdd(&cnt[i0],1);
      int pos1 = atomicAdd(&cnt[i1],1);
      idxp[t*2]=i0; idxp[t*2+1]=i1;
      posp[t*2]=pos0; posp[t*2+1]=pos1;
      wvp[t*2]=w0; wvp[t*2+1]=w1;
    }
  }
}

// ---- plan ----
__global__ void plan_kernel(const int* __restrict__ cnt, int* __restrict__ offs,
                            int* __restrict__ tiles, int* __restrict__ ntiles)
{
  int o=0, n=0;
  for (int e=0;e<E_NUM;e++){
    offs[e]=o;
    int c=cnt[e];
    int nt=(c+BM-1)/BM;
    for (int m=0;m<nt;m++) tiles[n++] = (e<<16)|m;
    o+=c;
  }
  offs[E_NUM]=o;
  *ntiles=n;
}

// ---- scatter ----
__global__ void scatter_kernel(const int* __restrict__ idxp, const int* __restrict__ posp,
                               const float* __restrict__ wvp, const int* __restrict__ offs,
                               int* __restrict__ tok_of, float* __restrict__ w_of,
                               int* __restrict__ slot_of)
{
  int i = blockIdx.x*blockDim.x + threadIdx.x;
  if (i >= SLOTS) return;
  int t = i>>1, k = i&1;
  int e = idxp[t*2+k];
  int slot = offs[e] + posp[t*2+k];
  tok_of[slot] = t;
  w_of[slot]   = wvp[t*2+k];
  slot_of[t*2+k] = slot;
}

// ---- gather (locality materialization; r12 proved removing it costs 3x L2 traffic) ----
__global__ __launch_bounds__(256) void gather_kernel(
    const float* __restrict__ x, const int* __restrict__ tok_of,
    unsigned short* __restrict__ Xg)
{
  int slot = blockIdx.x;
  int t = tok_of[slot];
  const float4* src = (const float4*)(x + (size_t)t*H_DIM);
  float4 v = src[threadIdx.x];
  ushort4 o;
  o.x=f2bf(v.x); o.y=f2bf(v.y); o.z=f2bf(v.z); o.w=f2bf(v.w);
  ((ushort4*)(Xg + (size_t)slot*H_DIM))[threadIdx.x] = o;
}

// ---- transpose + convert, W1 and W2 in ONE launch (linearized grid) ----
// W1: [8][1024][4096] -> W1t [8][4096][1024];  W2: [8][4096][1024] -> W2t [8][1024][4096]
__global__ __launch_bounds__(256) void transconv2_kernel(
    const float* __restrict__ W1, unsigned short* __restrict__ W1t,
    const float* __restrict__ W2, unsigned short* __restrict__ W2t)
{
  __shared__ float tile[64][65];
  int id = blockIdx.x;
  const float* in; unsigned short* out; int R, C, cx, cy, e;
  if (id < 8192){            // W1: R=1024(H), C=4096(FF): 64 x-blocks * 16 y-blocks
    e = id >> 10; int rem = id & 1023;
    cx = rem & 63; cy = rem >> 6;        // cx: C/64=64, cy: R/64=16
    R = H_DIM; C = FF_DIM; in = W1; out = W1t;
  } else {                   // W2: R=4096(FF), C=1024(H): 16 x-blocks * 64 y-blocks
    int id2 = id - 8192;
    e = id2 >> 10; int rem = id2 & 1023;
    cx = rem & 15; cy = rem >> 4;        // cx: C/64=16, cy: R/64=64
    R = FF_DIM; C = H_DIM; in = W2; out = W2t;
  }
  const float* inp = in + (size_t)e*R*C;
  unsigned short* op = out + (size_t)e*R*C;
  int c0 = cx*64, r0 = cy*64;
  int tx = threadIdx.x & 15, ty = threadIdx.x >> 4;
  #pragma unroll
  for (int i=0;i<4;i++){
    int r = i*16 + ty;
    float4 v = *(const float4*)(inp + (size_t)(r0+r)*C + c0 + tx*4);
    tile[r][tx*4+0]=v.x; tile[r][tx*4+1]=v.y; tile[r][tx*4+2]=v.z; tile[r][tx*4+3]=v.w;
  }
  __syncthreads();
  int wx = threadIdx.x & 7;
  int wcl = threadIdx.x >> 3;
  #pragma unroll
  for (int i=0;i<2;i++){
    int c = i*32 + wcl;
    u16x8 o;
    #pragma unroll
    for (int j=0;j<8;j++) o[j] = f2bf(tile[wx*8+j][c]);
    *(u16x8*)(op + (size_t)(c0+c)*R + r0 + wx*8) = o;
  }
}

#define GLDS(g, l) __builtin_amdgcn_global_load_lds((global_cvoid*)(g), (lds_void*)(l), 16, 0, 0)

// ==== grouped GEMM (r8 core): 128x128, BK=32, 256 thr, dbuf, depth-2 counted
// vmcnt(4), 2-way-max swizzle, chunked XCD mapping (chunk = 4 tiles x 4 cols
// pinned to XCD blockIdx&7). launch_bounds(256,5): 5 x 32KB = 160KB -> 5
// blocks/CU for cross-block latency hiding (the r7-proven lever).
// MODE 0: gelu(tanh-form) epilogue -> bf16 mid (max dev vs erf-gelu ~3e-4,
// far under the bf16 floor). MODE 1: gate-scale -> bf16 y. ====
template<int MODE>
__global__ __launch_bounds__(256, 5) void gemm128_kernel(
    const unsigned short* __restrict__ A,    // [slots][K]
    const unsigned short* __restrict__ Bt,   // [E][N][K]
    const float* __restrict__ bias,          // [E][N]
    unsigned short* __restrict__ Out,        // [slots][N]
    const int* __restrict__ tiles, const int* __restrict__ ntiles,
    const int* __restrict__ cnt, const int* __restrict__ offs,
    const float* __restrict__ w_of,
    int N, int K, int cpcs)                  // cpcs: log2(col-bands)
{
  // chunked mapping: L -> (xcd, slot) -> (chunk, within) -> (tile, col)
  int L = blockIdx.x;
  int xcd = L & 7;
  int slot = L >> 3;
  int within = slot & 15;
  int chunk = ((slot >> 4) << 3) + xcd;
  int tb = chunk >> cpcs;
  int cb = chunk & ((1<<cpcs)-1);
  int tile_id = tb*4 + (within & 3);
  if (tile_id >= *ntiles) return;
  int col0 = (cb*4 + (within >> 2)) << 7;

  int packed = tiles[tile_id];
  int e = packed>>16, mt = packed & 0xffff;
  int row0 = offs[e] + mt*BM;
  int nvalid = cnt[e] - mt*BM; if (nvalid > BM) nvalid = BM;
  const unsigned short* Be = Bt + (size_t)e*N*K;

  __shared__ unsigned short As[2][128*32];
  __shared__ unsigned short Bs[2][128*32];
  char* asb = (char*)&As[0][0];
  char* bsb = (char*)&Bs[0][0];

  int t = threadIdx.x;
  int wid = t>>6, lane = t&63;
  int wr = (wid>>1)*64, wc = (wid&1)*64;
  int fr = lane&15, fq = lane>>4;

  // staging: thread t -> row t>>2 (+64), phys chunk t&3;
  // source logical chunk scl = (phys - (row>>1))&3 (inverse of read swizzle)
  int srow = t>>2;
  int scl  = ((t&3) - ((t>>3)&3)) & 3;
  int sdst = wid*1024;

  const unsigned short* pA0 = A  + (size_t)(row0 + srow)*K      + scl*8;
  const unsigned short* pA1 = A  + (size_t)(row0 + 64 + srow)*K + scl*8;
  const unsigned short* pB0 = Be + (size_t)(col0 + srow)*K      + scl*8;
  const unsigned short* pB1 = Be + (size_t)(col0 + 64 + srow)*K + scl*8;

  auto stage = [&](int buf, int kelem){
    GLDS(pA0 + kelem, asb + buf*8192 + sdst);
    GLDS(pA1 + kelem, asb + buf*8192 + 4096 + sdst);
    GLDS(pB0 + kelem, bsb + buf*8192 + sdst);
    GLDS(pB1 + kelem, bsb + buf*8192 + 4096 + sdst);
  };

  int rd_sw = ((fq + ((fr>>1)&3)) & 3) << 4;

  f32x4 acc[4][4];
  #pragma unroll
  for (int i=0;i<4;i++)
    #pragma unroll
    for (int j=0;j<4;j++) acc[i][j] = (f32x4){0.f,0.f,0.f,0.f};

  int NT = K >> 5;
  stage(0, 0);
  stage(1, 32);
  for (int kt=0; kt<NT; ++kt){
    int cur = kt&1;
    if (kt+1 < NT) asm volatile("s_waitcnt vmcnt(4)" ::: "memory");
    else           asm volatile("s_waitcnt vmcnt(0)" ::: "memory");
    __builtin_amdgcn_s_barrier();
    asm volatile("" ::: "memory");

    s16x8 af[4], bfr[4];
    #pragma unroll
    for (int i=0;i<4;i++){
      af[i]  = *(const s16x8*)(asb + cur*8192 + (wr + i*16 + fr)*64 + rd_sw);
      bfr[i] = *(const s16x8*)(bsb + cur*8192 + (wc + i*16 + fr)*64 + rd_sw);
    }
    #pragma unroll
    for (int i=0;i<4;i++)
      #pragma unroll
      for (int j=0;j<4;j++)
        acc[i][j] = __builtin_amdgcn_mfma_f32_16x16x32_bf16(af[i], bfr[j], acc[i][j], 0,0,0);

    asm volatile("s_waitcnt lgkmcnt(0)" ::: "memory");
    __builtin_amdgcn_s_barrier();
    asm volatile("" ::: "memory");
    if (kt+2 < NT) stage(cur, (kt+2)*32);
  }

  // epilogue: C/D layout col=lane&15, row=(lane>>4)*4+reg. Bias hoisted.
  float bias_v[4];
  #pragma unroll
  for (int j=0;j<4;j++) bias_v[j] = bias[(size_t)e*N + col0 + wc + j*16 + fr];
  #pragma unroll
  for (int i=0;i<4;i++){
    #pragma unroll
    for (int r=0;r<4;r++){
      int lrow = wr + i*16 + fq*4 + r;
      if (lrow < nvalid){
        int grow = row0 + lrow;
        float scale = (MODE==1) ? w_of[grow] : 0.f;
        #pragma unroll
        for (int j=0;j<4;j++){
          int col = col0 + wc + j*16 + fr;
          float v = acc[i][j][r] + bias_v[j];
          if (MODE==0){
            // gelu, tanh form: v * (1 - 1/(e^{2u}+1)), u = 0.79788456(v + 0.044715 v^3)
            float u = v*(0.7978845608f + 0.0356774081f*v*v);
            float z = __expf(2.f*u);
            v = v - __fdividef(v, z + 1.f);
          } else {
            v *= scale;
          }
          Out[(size_t)grow*N + col] = f2bf(v);
        }
      }
    }
  }
}

// ---- combine: out[t] = y[slot0] + y[slot1] ----
__global__ __launch_bounds__(256) void combine_kernel(
    const unsigned short* __restrict__ y, const int* __restrict__ slot_of,
    float* __restrict__ out)
{
  int tok = blockIdx.x;
  int s0 = slot_of[tok*2], s1 = slot_of[tok*2+1];
  const ushort4* y0 = (const ushort4*)(y + (size_t)s0*H_DIM);
  const ushort4* y1 = (const ushort4*)(y + (size_t)s1*H_DIM);
  float4* o = (float4*)(out + (size_t)tok*H_DIM);
  ushort4 a = y0[threadIdx.x], b = y1[threadIdx.x];
  float4 r;
  r.x = bf2f(a.x)+bf2f(b.x);
  r.y = bf2f(a.y)+bf2f(b.y);
  r.z = bf2f(a.z)+bf2f(b.z);
  r.w = bf2f(a.w)+bf2f(b.w);
  o[threadIdx.x] = r;
}

extern "C" void kernel_launch(void* const* d_in, const int* in_sizes, int n_in,
                              void* d_out, int out_size, void* d_ws, size_t ws_size,
                              hipStream_t stream) {
  const float* x  = (const float*)d_in[0];
  const float* Wg = (const float*)d_in[1];
  const float* bg = (const float*)d_in[2];
  const float* W1 = (const float*)d_in[3];
  const float* b1 = (const float*)d_in[4];
  const float* W2 = (const float*)d_in[5];
  const float* b2 = (const float*)d_in[6];
  float* out = (float*)d_out;
  char* ws = (char*)d_ws;

  int*   cnt      = (int*)  (ws + OFF_CNT);
  int*   offs     = (int*)  (ws + OFF_OFFS);
  int*   ntiles   = (int*)  (ws + OFF_NT);
  int*   tiles    = (int*)  (ws + OFF_TILES);
  int*   idxp     = (int*)  (ws + OFF_IDX);
  int*   posp     = (int*)  (ws + OFF_POS);
  float* wvp      = (float*)(ws + OFF_WV);
  int*   slot_of  = (int*)  (ws + OFF_SLOT);
  int*   tok_of   = (int*)  (ws + OFF_TOK);
  float* w_of     = (float*)(ws + OFF_WOF);
  unsigned short* Xg  = (unsigned short*)(ws + OFF_XG);
  unsigned short* W1t = (unsigned short*)(ws + OFF_W1T);
  unsigned short* W2t = (unsigned short*)(ws + OFF_W2T);
  unsigned short* mid = (unsigned short*)(ws + OFF_MID);
  unsigned short* y   = (unsigned short*)(ws + OFF_Y);

  hipMemsetAsync(ws + OFF_CNT, 0, 32, stream);

  gate_kernel<<<T_TOK/4, 64, 0, stream>>>(x, Wg, bg, cnt, idxp, posp, wvp);
  plan_kernel<<<1, 1, 0, stream>>>(cnt, offs, tiles, ntiles);
  scatter_kernel<<<SLOTS/256, 256, 0, stream>>>(idxp, posp, wvp, offs, tok_of, w_of, slot_of);
  gather_kernel<<<SLOTS, 256, 0, stream>>>(x, tok_of, Xg);

  // W1 + W2 transpose/convert in one launch (8192 + 8192 blocks)
  transconv2_kernel<<<dim3(16384), 256, 0, stream>>>(W1, W1t, W2, W2t);

  // GEMM1: 18 tile-bands x 8 col-bands = 144 chunks -> 18 rounds x 128 = 2304
  gemm128_kernel<0><<<dim3(2304), 256, 0, stream>>>(
      Xg, W1t, b1, mid, tiles, ntiles, cnt, offs, nullptr, FF_DIM, H_DIM, 3);
  // GEMM2: 18 tile-bands x 2 col-bands = 36 chunks -> 5 rounds x 128 = 640
  gemm128_kernel<1><<<dim3(640), 256, 0, stream>>>(
      mid, W2t, b2, y, tiles, ntiles, cnt, offs, w_of, H_DIM, FF_DIM, 1);

  combine_kernel<<<T_TOK, 256, 0, stream>>>(y, slot_of, out);
}

// Round 16
// 423.038 us; speedup vs baseline: 1.8109x; 1.8109x over previous
//
#include <hip/hip_runtime.h>
#include <hip/hip_bf16.h>
#include <math.h>

// ---- problem constants ----
#define T_TOK  4096      // B*S tokens
#define H_DIM  1024
#define E_NUM  8
#define FF_DIM 4096
#define KSEL   2
#define SLOTS  (T_TOK*KSEL)     // 8192
#define SLOTS_PAD (SLOTS + 256)
#define BM 128
#define MAXTILES 72             // 128-row tiles (18 bands of 4)

typedef __attribute__((ext_vector_type(8))) short s16x8;
typedef __attribute__((ext_vector_type(8))) unsigned short u16x8;
typedef __attribute__((ext_vector_type(4))) float f32x4;

typedef __attribute__((address_space(1))) const void global_cvoid;
typedef __attribute__((address_space(3))) void lds_void;

__device__ __forceinline__ unsigned short f2bf(float f){
  unsigned int u = __float_as_uint(f);
  u += 0x7fffu + ((u>>16)&1u);
  return (unsigned short)(u>>16);
}
__device__ __forceinline__ float bf2f(unsigned short h){
  return __uint_as_float(((unsigned int)h)<<16);
}

// ---- workspace layout ----
static constexpr size_t OFF_CNT   = 0;
static constexpr size_t OFF_OFFS  = 256;
static constexpr size_t OFF_NT    = 512;
static constexpr size_t OFF_TILES = 768;
static constexpr size_t OFF_IDX   = 1280;
static constexpr size_t OFF_POS   = OFF_IDX  + 32768;
static constexpr size_t OFF_WV    = OFF_POS  + 32768;
static constexpr size_t OFF_SLOT  = OFF_WV   + 32768;   // [T][2] int
static constexpr size_t OFF_TOK   = OFF_SLOT + 32768;   // [SLOTS] int
static constexpr size_t OFF_WOF   = OFF_TOK  + 32768;   // [SLOTS] float
static constexpr size_t OFF_XG    = OFF_WOF  + 32768;                       // [SLOTS_PAD][H] bf16
static constexpr size_t OFF_W1T   = OFF_XG  + (size_t)SLOTS_PAD*H_DIM*2;    // [E][FF][H] bf16
static constexpr size_t OFF_W2T   = OFF_W1T + (size_t)E_NUM*H_DIM*FF_DIM*2; // [E][H][FF] bf16
static constexpr size_t OFF_MID   = OFF_W2T + (size_t)E_NUM*H_DIM*FF_DIM*2; // [SLOTS_PAD][FF] bf16
static constexpr size_t OFF_Y     = OFF_MID + (size_t)SLOTS_PAD*FF_DIM*2;   // [SLOTS][H] bf16

// ---- gating: 4 tokens per block (validated r10) ----
__global__ __launch_bounds__(64) void gate_kernel(
    const float* __restrict__ x, const float* __restrict__ Wg,
    const float* __restrict__ bg, int* __restrict__ cnt,
    int* __restrict__ idxp, int* __restrict__ posp, float* __restrict__ wvp)
{
  int lane = threadIdx.x;
  for (int tt=0; tt<4; ++tt){
    int t = blockIdx.x*4 + tt;
    const float* xr = x + (size_t)t*H_DIM;
    float acc[E_NUM];
    #pragma unroll
    for (int e=0;e<E_NUM;e++) acc[e]=0.f;
    for (int i=0;i<H_DIM/64;i++){
      int h = i*64 + lane;
      float xv = xr[h];
      const float* wr_ = Wg + (size_t)h*E_NUM;
      #pragma unroll
      for (int e=0;e<E_NUM;e++) acc[e] += xv*wr_[e];
    }
    #pragma unroll
    for (int e=0;e<E_NUM;e++){
      #pragma unroll
      for (int off=32; off>0; off>>=1) acc[e] += __shfl_xor(acc[e], off);
    }
    if (lane==0){
      float l[E_NUM];
      #pragma unroll
      for (int e=0;e<E_NUM;e++) l[e] = acc[e] + bg[e];
      int i0 = 0;
      #pragma unroll
      for (int e=1;e<E_NUM;e++) if (l[e] > l[i0]) i0 = e;
      int i1 = (i0==0)?1:0;
      #pragma unroll
      for (int e=0;e<E_NUM;e++) if (e!=i0 && l[e] > l[i1]) i1 = e;
      float p1 = expf(l[i1]-l[i0]);
      float s  = 1.f + p1;
      float w0 = 1.f/s, w1 = p1/s;
      int pos0 = atomicAdd(&cnt[i0],1);
      int pos1 = atomicAdd(&cnt[i1],1);
      idxp[t*2]=i0; idxp[t*2+1]=i1;
      posp[t*2]=pos0; posp[t*2+1]=pos1;
      wvp[t*2]=w0; wvp[t*2+1]=w1;
    }
  }
}

// ---- plan ----
__global__ void plan_kernel(const int* __restrict__ cnt, int* __restrict__ offs,
                            int* __restrict__ tiles, int* __restrict__ ntiles)
{
  int o=0, n=0;
  for (int e=0;e<E_NUM;e++){
    offs[e]=o;
    int c=cnt[e];
    int nt=(c+BM-1)/BM;
    for (int m=0;m<nt;m++) tiles[n++] = (e<<16)|m;
    o+=c;
  }
  offs[E_NUM]=o;
  *ntiles=n;
}

// ---- scatter ----
__global__ void scatter_kernel(const int* __restrict__ idxp, const int* __restrict__ posp,
                               const float* __restrict__ wvp, const int* __restrict__ offs,
                               int* __restrict__ tok_of, float* __restrict__ w_of,
                               int* __restrict__ slot_of)
{
  int i = blockIdx.x*blockDim.x + threadIdx.x;
  if (i >= SLOTS) return;
  int t = i>>1, k = i&1;
  int e = idxp[t*2+k];
  int slot = offs[e] + posp[t*2+k];
  tok_of[slot] = t;
  w_of[slot]   = wvp[t*2+k];
  slot_of[t*2+k] = slot;
}

// ---- gather (locality materialization; r12 proved removing it costs 3x L2 traffic) ----
__global__ __launch_bounds__(256) void gather_kernel(
    const float* __restrict__ x, const int* __restrict__ tok_of,
    unsigned short* __restrict__ Xg)
{
  int slot = blockIdx.x;
  int t = tok_of[slot];
  const float4* src = (const float4*)(x + (size_t)t*H_DIM);
  float4 v = src[threadIdx.x];
  ushort4 o;
  o.x=f2bf(v.x); o.y=f2bf(v.y); o.z=f2bf(v.z); o.w=f2bf(v.w);
  ((ushort4*)(Xg + (size_t)slot*H_DIM))[threadIdx.x] = o;
}

// ---- transpose + convert, W1 and W2 in ONE launch ----
__global__ __launch_bounds__(256) void transconv2_kernel(
    const float* __restrict__ W1, unsigned short* __restrict__ W1t,
    const float* __restrict__ W2, unsigned short* __restrict__ W2t)
{
  __shared__ float tile[64][65];
  int id = blockIdx.x;
  const float* in; unsigned short* out; int R, C, cx, cy, e;
  if (id < 8192){            // W1: R=1024(H), C=4096(FF)
    e = id >> 10; int rem = id & 1023;
    cx = rem & 63; cy = rem >> 6;
    R = H_DIM; C = FF_DIM; in = W1; out = W1t;
  } else {                   // W2: R=4096(FF), C=1024(H)
    int id2 = id - 8192;
    e = id2 >> 10; int rem = id2 & 1023;
    cx = rem & 15; cy = rem >> 4;
    R = FF_DIM; C = H_DIM; in = W2; out = W2t;
  }
  const float* inp = in + (size_t)e*R*C;
  unsigned short* op = out + (size_t)e*R*C;
  int c0 = cx*64, r0 = cy*64;
  int tx = threadIdx.x & 15, ty = threadIdx.x >> 4;
  #pragma unroll
  for (int i=0;i<4;i++){
    int r = i*16 + ty;
    float4 v = *(const float4*)(inp + (size_t)(r0+r)*C + c0 + tx*4);
    tile[r][tx*4+0]=v.x; tile[r][tx*4+1]=v.y; tile[r][tx*4+2]=v.z; tile[r][tx*4+3]=v.w;
  }
  __syncthreads();
  int wx = threadIdx.x & 7;
  int wcl = threadIdx.x >> 3;
  #pragma unroll
  for (int i=0;i<2;i++){
    int c = i*32 + wcl;
    u16x8 o;
    #pragma unroll
    for (int j=0;j<8;j++) o[j] = f2bf(tile[wx*8+j][c]);
    *(u16x8*)(op + (size_t)(c0+c)*R + r0 + wx*8) = o;
  }
}

#define GLDS(g, l) __builtin_amdgcn_global_load_lds((global_cvoid*)(g), (lds_void*)(l), 16, 0, 0)

// ==== grouped GEMM (r8 core EXACT envelope: launch_bounds(256,4) -> VGPR 56,
// no spill): 128x128, BK=32, 256 thr, dbuf, depth-2 counted vmcnt(4),
// 2-way-max swizzle, chunked XCD mapping. MODE 0: tanh-gelu epilogue -> mid.
// MODE 1: gate-scale -> y. (r15 lesson: (256,5) forced VGPR 48 -> acc spilled
// to scratch, 507 MB writes, 2x regression. Never starve the accumulators.) ====
template<int MODE>
__global__ __launch_bounds__(256, 4) void gemm128_kernel(
    const unsigned short* __restrict__ A,    // [slots][K]
    const unsigned short* __restrict__ Bt,   // [E][N][K]
    const float* __restrict__ bias,          // [E][N]
    unsigned short* __restrict__ Out,        // [slots][N]
    const int* __restrict__ tiles, const int* __restrict__ ntiles,
    const int* __restrict__ cnt, const int* __restrict__ offs,
    const float* __restrict__ w_of,
    int N, int K, int cpcs)                  // cpcs: log2(col-bands)
{
  // chunked mapping: L -> (xcd, slot) -> (chunk, within) -> (tile, col)
  int L = blockIdx.x;
  int xcd = L & 7;
  int slot = L >> 3;
  int within = slot & 15;
  int chunk = ((slot >> 4) << 3) + xcd;
  int tb = chunk >> cpcs;
  int cb = chunk & ((1<<cpcs)-1);
  int tile_id = tb*4 + (within & 3);
  if (tile_id >= *ntiles) return;
  int col0 = (cb*4 + (within >> 2)) << 7;

  int packed = tiles[tile_id];
  int e = packed>>16, mt = packed & 0xffff;
  int row0 = offs[e] + mt*BM;
  int nvalid = cnt[e] - mt*BM; if (nvalid > BM) nvalid = BM;
  const unsigned short* Be = Bt + (size_t)e*N*K;

  __shared__ unsigned short As[2][128*32];
  __shared__ unsigned short Bs[2][128*32];
  char* asb = (char*)&As[0][0];
  char* bsb = (char*)&Bs[0][0];

  int t = threadIdx.x;
  int wid = t>>6, lane = t&63;
  int wr = (wid>>1)*64, wc = (wid&1)*64;
  int fr = lane&15, fq = lane>>4;

  int srow = t>>2;
  int scl  = ((t&3) - ((t>>3)&3)) & 3;
  int sdst = wid*1024;

  const unsigned short* pA0 = A  + (size_t)(row0 + srow)*K      + scl*8;
  const unsigned short* pA1 = A  + (size_t)(row0 + 64 + srow)*K + scl*8;
  const unsigned short* pB0 = Be + (size_t)(col0 + srow)*K      + scl*8;
  const unsigned short* pB1 = Be + (size_t)(col0 + 64 + srow)*K + scl*8;

  auto stage = [&](int buf, int kelem){
    GLDS(pA0 + kelem, asb + buf*8192 + sdst);
    GLDS(pA1 + kelem, asb + buf*8192 + 4096 + sdst);
    GLDS(pB0 + kelem, bsb + buf*8192 + sdst);
    GLDS(pB1 + kelem, bsb + buf*8192 + 4096 + sdst);
  };

  int rd_sw = ((fq + ((fr>>1)&3)) & 3) << 4;

  f32x4 acc[4][4];
  #pragma unroll
  for (int i=0;i<4;i++)
    #pragma unroll
    for (int j=0;j<4;j++) acc[i][j] = (f32x4){0.f,0.f,0.f,0.f};

  int NT = K >> 5;
  stage(0, 0);
  stage(1, 32);
  for (int kt=0; kt<NT; ++kt){
    int cur = kt&1;
    if (kt+1 < NT) asm volatile("s_waitcnt vmcnt(4)" ::: "memory");
    else           asm volatile("s_waitcnt vmcnt(0)" ::: "memory");
    __builtin_amdgcn_s_barrier();
    asm volatile("" ::: "memory");

    s16x8 af[4], bfr[4];
    #pragma unroll
    for (int i=0;i<4;i++){
      af[i]  = *(const s16x8*)(asb + cur*8192 + (wr + i*16 + fr)*64 + rd_sw);
      bfr[i] = *(const s16x8*)(bsb + cur*8192 + (wc + i*16 + fr)*64 + rd_sw);
    }
    #pragma unroll
    for (int i=0;i<4;i++)
      #pragma unroll
      for (int j=0;j<4;j++)
        acc[i][j] = __builtin_amdgcn_mfma_f32_16x16x32_bf16(af[i], bfr[j], acc[i][j], 0,0,0);

    asm volatile("s_waitcnt lgkmcnt(0)" ::: "memory");
    __builtin_amdgcn_s_barrier();
    asm volatile("" ::: "memory");
    if (kt+2 < NT) stage(cur, (kt+2)*32);
  }

  // epilogue: C/D layout col=lane&15, row=(lane>>4)*4+reg. Bias hoisted.
  float bias_v[4];
  #pragma unroll
  for (int j=0;j<4;j++) bias_v[j] = bias[(size_t)e*N + col0 + wc + j*16 + fr];
  #pragma unroll
  for (int i=0;i<4;i++){
    #pragma unroll
    for (int r=0;r<4;r++){
      int lrow = wr + i*16 + fq*4 + r;
      if (lrow < nvalid){
        int grow = row0 + lrow;
        float scale = (MODE==1) ? w_of[grow] : 0.f;
        #pragma unroll
        for (int j=0;j<4;j++){
          int col = col0 + wc + j*16 + fr;
          float v = acc[i][j][r] + bias_v[j];
          if (MODE==0){
            // gelu, tanh form: v - v/(e^{2u}+1), u = 0.79788456(v + 0.044715 v^3)
            float u = v*(0.7978845608f + 0.0356774081f*v*v);
            float z = __expf(2.f*u);
            v = v - __fdividef(v, z + 1.f);
          } else {
            v *= scale;
          }
          Out[(size_t)grow*N + col] = f2bf(v);
        }
      }
    }
  }
}

// ---- combine: out[t] = y[slot0] + y[slot1] ----
__global__ __launch_bounds__(256) void combine_kernel(
    const unsigned short* __restrict__ y, const int* __restrict__ slot_of,
    float* __restrict__ out)
{
  int tok = blockIdx.x;
  int s0 = slot_of[tok*2], s1 = slot_of[tok*2+1];
  const ushort4* y0 = (const ushort4*)(y + (size_t)s0*H_DIM);
  const ushort4* y1 = (const ushort4*)(y + (size_t)s1*H_DIM);
  float4* o = (float4*)(out + (size_t)tok*H_DIM);
  ushort4 a = y0[threadIdx.x], b = y1[threadIdx.x];
  float4 r;
  r.x = bf2f(a.x)+bf2f(b.x);
  r.y = bf2f(a.y)+bf2f(b.y);
  r.z = bf2f(a.z)+bf2f(b.z);
  r.w = bf2f(a.w)+bf2f(b.w);
  o[threadIdx.x] = r;
}

extern "C" void kernel_launch(void* const* d_in, const int* in_sizes, int n_in,
                              void* d_out, int out_size, void* d_ws, size_t ws_size,
                              hipStream_t stream) {
  const float* x  = (const float*)d_in[0];
  const float* Wg = (const float*)d_in[1];
  const float* bg = (const float*)d_in[2];
  const float* W1 = (const float*)d_in[3];
  const float* b1 = (const float*)d_in[4];
  const float* W2 = (const float*)d_in[5];
  const float* b2 = (const float*)d_in[6];
  float* out = (float*)d_out;
  char* ws = (char*)d_ws;

  int*   cnt      = (int*)  (ws + OFF_CNT);
  int*   offs     = (int*)  (ws + OFF_OFFS);
  int*   ntiles   = (int*)  (ws + OFF_NT);
  int*   tiles    = (int*)  (ws + OFF_TILES);
  int*   idxp     = (int*)  (ws + OFF_IDX);
  int*   posp     = (int*)  (ws + OFF_POS);
  float* wvp      = (float*)(ws + OFF_WV);
  int*   slot_of  = (int*)  (ws + OFF_SLOT);
  int*   tok_of   = (int*)  (ws + OFF_TOK);
  float* w_of     = (float*)(ws + OFF_WOF);
  unsigned short* Xg  = (unsigned short*)(ws + OFF_XG);
  unsigned short* W1t = (unsigned short*)(ws + OFF_W1T);
  unsigned short* W2t = (unsigned short*)(ws + OFF_W2T);
  unsigned short* mid = (unsigned short*)(ws + OFF_MID);
  unsigned short* y   = (unsigned short*)(ws + OFF_Y);

  hipMemsetAsync(ws + OFF_CNT, 0, 32, stream);

  gate_kernel<<<T_TOK/4, 64, 0, stream>>>(x, Wg, bg, cnt, idxp, posp, wvp);
  plan_kernel<<<1, 1, 0, stream>>>(cnt, offs, tiles, ntiles);
  scatter_kernel<<<SLOTS/256, 256, 0, stream>>>(idxp, posp, wvp, offs, tok_of, w_of, slot_of);
  gather_kernel<<<SLOTS, 256, 0, stream>>>(x, tok_of, Xg);

  // W1 + W2 transpose/convert in one launch
  transconv2_kernel<<<dim3(16384), 256, 0, stream>>>(W1, W1t, W2, W2t);

  // GEMM1: 18 tile-bands x 8 col-bands = 144 chunks -> 18 rounds x 128 = 2304
  gemm128_kernel<0><<<dim3(2304), 256, 0, stream>>>(
      Xg, W1t, b1, mid, tiles, ntiles, cnt, offs, nullptr, FF_DIM, H_DIM, 3);
  // GEMM2: 18 tile-bands x 2 col-bands = 36 chunks -> 5 rounds x 128 = 640
  gemm128_kernel<1><<<dim3(640), 256, 0, stream>>>(
      mid, W2t, b2, y, tiles, ntiles, cnt, offs, w_of, H_DIM, FF_DIM, 1);

  combine_kernel<<<T_TOK, 256, 0, stream>>>(y, slot_of, out);
}

// Round 17
// 419.899 us; speedup vs baseline: 1.8244x; 1.0075x over previous
//
#include <hip/hip_runtime.h>
#include <hip/hip_bf16.h>
#include <math.h>

// ---- problem constants ----
#define T_TOK  4096      // B*S tokens
#define H_DIM  1024
#define E_NUM  8
#define FF_DIM 4096
#define KSEL   2
#define SLOTS  (T_TOK*KSEL)     // 8192
#define SLOTS_PAD (SLOTS + 256)
#define BM 128
#define MAXTILES 72             // 128-row tiles (18 bands of 4)

typedef __attribute__((ext_vector_type(8))) short s16x8;
typedef __attribute__((ext_vector_type(8))) unsigned short u16x8;
typedef __attribute__((ext_vector_type(4))) float f32x4;

typedef __attribute__((address_space(1))) const void global_cvoid;
typedef __attribute__((address_space(3))) void lds_void;

__device__ __forceinline__ unsigned short f2bf(float f){
  unsigned int u = __float_as_uint(f);
  u += 0x7fffu + ((u>>16)&1u);
  return (unsigned short)(u>>16);
}
__device__ __forceinline__ float bf2f(unsigned short h){
  return __uint_as_float(((unsigned int)h)<<16);
}

// ---- workspace layout ----
static constexpr size_t OFF_CNT   = 0;                  // 8 ints
static constexpr size_t OFF_IDX   = 1280;               // [T][2] int
static constexpr size_t OFF_POS   = OFF_IDX  + 32768;
static constexpr size_t OFF_WV    = OFF_POS  + 32768;
static constexpr size_t OFF_SLOT  = OFF_WV   + 32768;   // [T][2] int
static constexpr size_t OFF_WOF   = OFF_SLOT + 32768;   // [SLOTS] float
static constexpr size_t OFF_XG    = OFF_WOF  + 32768;                       // [SLOTS_PAD][H] bf16
static constexpr size_t OFF_W1T   = OFF_XG  + (size_t)SLOTS_PAD*H_DIM*2;    // [E][FF][H] bf16
static constexpr size_t OFF_W2T   = OFF_W1T + (size_t)E_NUM*H_DIM*FF_DIM*2; // [E][H][FF] bf16
static constexpr size_t OFF_MID   = OFF_W2T + (size_t)E_NUM*H_DIM*FF_DIM*2; // [SLOTS_PAD][FF] bf16
static constexpr size_t OFF_Y     = OFF_MID + (size_t)SLOTS_PAD*FF_DIM*2;   // [SLOTS][H] bf16

// ---- gating: 4 tokens per block (validated r10) ----
__global__ __launch_bounds__(64) void gate_kernel(
    const float* __restrict__ x, const float* __restrict__ Wg,
    const float* __restrict__ bg, int* __restrict__ cnt,
    int* __restrict__ idxp, int* __restrict__ posp, float* __restrict__ wvp)
{
  int lane = threadIdx.x;
  for (int tt=0; tt<4; ++tt){
    int t = blockIdx.x*4 + tt;
    const float* xr = x + (size_t)t*H_DIM;
    float acc[E_NUM];
    #pragma unroll
    for (int e=0;e<E_NUM;e++) acc[e]=0.f;
    for (int i=0;i<H_DIM/64;i++){
      int h = i*64 + lane;
      float xv = xr[h];
      const float* wr_ = Wg + (size_t)h*E_NUM;
      #pragma unroll
      for (int e=0;e<E_NUM;e++) acc[e] += xv*wr_[e];
    }
    #pragma unroll
    for (int e=0;e<E_NUM;e++){
      #pragma unroll
      for (int off=32; off>0; off>>=1) acc[e] += __shfl_xor(acc[e], off);
    }
    if (lane==0){
      float l[E_NUM];
      #pragma unroll
      for (int e=0;e<E_NUM;e++) l[e] = acc[e] + bg[e];
      int i0 = 0;
      #pragma unroll
      for (int e=1;e<E_NUM;e++) if (l[e] > l[i0]) i0 = e;
      int i1 = (i0==0)?1:0;
      #pragma unroll
      for (int e=0;e<E_NUM;e++) if (e!=i0 && l[e] > l[i1]) i1 = e;
      float p1 = expf(l[i1]-l[i0]);
      float s  = 1.f + p1;
      float w0 = 1.f/s, w1 = p1/s;
      int pos0 = atomicAdd(&cnt[i0],1);
      int pos1 = atomicAdd(&cnt[i1],1);
      idxp[t*2]=i0; idxp[t*2+1]=i1;
      posp[t*2]=pos0; posp[t*2+1]=pos1;
      wvp[t*2]=w0; wvp[t*2+1]=w1;
    }
  }
}

// ---- route + gather fused: slot = prefix(cnt)[e] + pos; copy token row ----
// (replaces plan + scatter + gather: the 8-value prefix sum is recomputed
// locally from cnt -- 8 L2-hot loads beats a serial planner kernel)
__global__ __launch_bounds__(256) void route_gather_kernel(
    const float* __restrict__ x, const int* __restrict__ idxp,
    const int* __restrict__ posp, const float* __restrict__ wvp,
    const int* __restrict__ cnt,
    unsigned short* __restrict__ Xg, float* __restrict__ w_of,
    int* __restrict__ slot_of)
{
  int b = blockIdx.x;            // 0..SLOTS-1 : (token t, choice k)
  int t = b>>1;
  int e = idxp[b];
  int off = 0;
  #pragma unroll
  for (int i=0;i<E_NUM;i++) off += (i<e) ? cnt[i] : 0;
  int slot = off + posp[b];
  const float4* src = (const float4*)(x + (size_t)t*H_DIM);
  float4 v = src[threadIdx.x];
  ushort4 o;
  o.x=f2bf(v.x); o.y=f2bf(v.y); o.z=f2bf(v.z); o.w=f2bf(v.w);
  ((ushort4*)(Xg + (size_t)slot*H_DIM))[threadIdx.x] = o;
  if (threadIdx.x == 0){
    w_of[slot] = wvp[b];
    slot_of[b] = slot;
  }
}

// ---- transpose + convert, W1 and W2 in ONE launch ----
__global__ __launch_bounds__(256) void transconv2_kernel(
    const float* __restrict__ W1, unsigned short* __restrict__ W1t,
    const float* __restrict__ W2, unsigned short* __restrict__ W2t)
{
  __shared__ float tile[64][65];
  int id = blockIdx.x;
  const float* in; unsigned short* out; int R, C, cx, cy, e;
  if (id < 8192){            // W1: R=1024(H), C=4096(FF)
    e = id >> 10; int rem = id & 1023;
    cx = rem & 63; cy = rem >> 6;
    R = H_DIM; C = FF_DIM; in = W1; out = W1t;
  } else {                   // W2: R=4096(FF), C=1024(H)
    int id2 = id - 8192;
    e = id2 >> 10; int rem = id2 & 1023;
    cx = rem & 15; cy = rem >> 4;
    R = FF_DIM; C = H_DIM; in = W2; out = W2t;
  }
  const float* inp = in + (size_t)e*R*C;
  unsigned short* op = out + (size_t)e*R*C;
  int c0 = cx*64, r0 = cy*64;
  int tx = threadIdx.x & 15, ty = threadIdx.x >> 4;
  #pragma unroll
  for (int i=0;i<4;i++){
    int r = i*16 + ty;
    float4 v = *(const float4*)(inp + (size_t)(r0+r)*C + c0 + tx*4);
    tile[r][tx*4+0]=v.x; tile[r][tx*4+1]=v.y; tile[r][tx*4+2]=v.z; tile[r][tx*4+3]=v.w;
  }
  __syncthreads();
  int wx = threadIdx.x & 7;
  int wcl = threadIdx.x >> 3;
  #pragma unroll
  for (int i=0;i<2;i++){
    int c = i*32 + wcl;
    u16x8 o;
    #pragma unroll
    for (int j=0;j<8;j++) o[j] = f2bf(tile[wx*8+j][c]);
    *(u16x8*)(op + (size_t)(c0+c)*R + r0 + wx*8) = o;
  }
}

#define GLDS(g, l) __builtin_amdgcn_global_load_lds((global_cvoid*)(g), (lds_void*)(l), 16, 0, 0)

// ==== grouped GEMM (r8/r16 core, frozen): 128x128, BK=32, 256 thr, dbuf,
// depth-2 counted vmcnt(4), 2-way-max swizzle, chunked XCD mapping,
// launch_bounds(256,4) (r15: (256,5) spilled acc -> 2x regression).
// Tile list computed IN-KERNEL from cnt (plan kernel eliminated).
// MODE 0: tanh-gelu -> mid. MODE 1: gate-scale -> y. ====
template<int MODE>
__global__ __launch_bounds__(256, 4) void gemm128_kernel(
    const unsigned short* __restrict__ A,    // [slots][K]
    const unsigned short* __restrict__ Bt,   // [E][N][K]
    const float* __restrict__ bias,          // [E][N]
    unsigned short* __restrict__ Out,        // [slots][N]
    const int* __restrict__ cnt,
    const float* __restrict__ w_of,
    int N, int K, int cpcs)                  // cpcs: log2(col-bands)
{
  // chunked mapping: L -> (xcd, slot) -> (chunk, within) -> (tile, col)
  int L = blockIdx.x;
  int xcd = L & 7;
  int slot = L >> 3;
  int within = slot & 15;
  int chunk = ((slot >> 4) << 3) + xcd;
  int tb = chunk >> cpcs;
  int cb = chunk & ((1<<cpcs)-1);
  int tile_id = tb*4 + (within & 3);
  int col0 = (cb*4 + (within >> 2)) << 7;

  // resolve (expert, tile-in-expert) from cnt prefix (uniform 8-iter loop)
  int e=0, row0=0, nv=0, acc_t=0, o=0, found=0;
  #pragma unroll
  for (int i=0;i<E_NUM;i++){
    int c = cnt[i];
    int nt = (c + BM-1) >> 7;
    if (!found && tile_id < acc_t + nt){
      int mt = tile_id - acc_t;
      e = i; row0 = o + mt*BM; nv = c - mt*BM; found = 1;
    }
    acc_t += nt; o += c;
  }
  if (!found) return;
  int nvalid = nv > BM ? BM : nv;
  const unsigned short* Be = Bt + (size_t)e*N*K;

  __shared__ unsigned short As[2][128*32];
  __shared__ unsigned short Bs[2][128*32];
  char* asb = (char*)&As[0][0];
  char* bsb = (char*)&Bs[0][0];

  int t = threadIdx.x;
  int wid = t>>6, lane = t&63;
  int wr = (wid>>1)*64, wc = (wid&1)*64;
  int fr = lane&15, fq = lane>>4;

  // staging: thread t -> row t>>2 (+64), phys chunk t&3;
  // source logical chunk scl = (phys - (row>>1))&3 (inverse of read swizzle)
  int srow = t>>2;
  int scl  = ((t&3) - ((t>>3)&3)) & 3;
  int sdst = wid*1024;

  const unsigned short* pA0 = A  + (size_t)(row0 + srow)*K      + scl*8;
  const unsigned short* pA1 = A  + (size_t)(row0 + 64 + srow)*K + scl*8;
  const unsigned short* pB0 = Be + (size_t)(col0 + srow)*K      + scl*8;
  const unsigned short* pB1 = Be + (size_t)(col0 + 64 + srow)*K + scl*8;

  auto stage = [&](int buf, int kelem){
    GLDS(pA0 + kelem, asb + buf*8192 + sdst);
    GLDS(pA1 + kelem, asb + buf*8192 + 4096 + sdst);
    GLDS(pB0 + kelem, bsb + buf*8192 + sdst);
    GLDS(pB1 + kelem, bsb + buf*8192 + 4096 + sdst);
  };

  int rd_sw = ((fq + ((fr>>1)&3)) & 3) << 4;

  f32x4 acc[4][4];
  #pragma unroll
  for (int i=0;i<4;i++)
    #pragma unroll
    for (int j=0;j<4;j++) acc[i][j] = (f32x4){0.f,0.f,0.f,0.f};

  int NT = K >> 5;
  stage(0, 0);
  stage(1, 32);
  for (int kt=0; kt<NT; ++kt){
    int cur = kt&1;
    if (kt+1 < NT) asm volatile("s_waitcnt vmcnt(4)" ::: "memory");
    else           asm volatile("s_waitcnt vmcnt(0)" ::: "memory");
    __builtin_amdgcn_s_barrier();
    asm volatile("" ::: "memory");

    s16x8 af[4], bfr[4];
    #pragma unroll
    for (int i=0;i<4;i++){
      af[i]  = *(const s16x8*)(asb + cur*8192 + (wr + i*16 + fr)*64 + rd_sw);
      bfr[i] = *(const s16x8*)(bsb + cur*8192 + (wc + i*16 + fr)*64 + rd_sw);
    }
    #pragma unroll
    for (int i=0;i<4;i++)
      #pragma unroll
      for (int j=0;j<4;j++)
        acc[i][j] = __builtin_amdgcn_mfma_f32_16x16x32_bf16(af[i], bfr[j], acc[i][j], 0,0,0);

    asm volatile("s_waitcnt lgkmcnt(0)" ::: "memory");
    __builtin_amdgcn_s_barrier();
    asm volatile("" ::: "memory");
    if (kt+2 < NT) stage(cur, (kt+2)*32);
  }

  // epilogue: C/D layout col=lane&15, row=(lane>>4)*4+reg. Bias hoisted.
  float bias_v[4];
  #pragma unroll
  for (int j=0;j<4;j++) bias_v[j] = bias[(size_t)e*N + col0 + wc + j*16 + fr];
  #pragma unroll
  for (int i=0;i<4;i++){
    #pragma unroll
    for (int r=0;r<4;r++){
      int lrow = wr + i*16 + fq*4 + r;
      if (lrow < nvalid){
        int grow = row0 + lrow;
        float scale = (MODE==1) ? w_of[grow] : 0.f;
        #pragma unroll
        for (int j=0;j<4;j++){
          int col = col0 + wc + j*16 + fr;
          float v = acc[i][j][r] + bias_v[j];
          if (MODE==0){
            // gelu, tanh form: v - v/(e^{2u}+1), u = 0.79788456(v + 0.044715 v^3)
            float u = v*(0.7978845608f + 0.0356774081f*v*v);
            float z = __expf(2.f*u);
            v = v - __fdividef(v, z + 1.f);
          } else {
            v *= scale;
          }
          Out[(size_t)grow*N + col] = f2bf(v);
        }
      }
    }
  }
}

// ---- combine: out[t] = y[slot0] + y[slot1] ----
__global__ __launch_bounds__(256) void combine_kernel(
    const unsigned short* __restrict__ y, const int* __restrict__ slot_of,
    float* __restrict__ out)
{
  int tok = blockIdx.x;
  int s0 = slot_of[tok*2], s1 = slot_of[tok*2+1];
  const ushort4* y0 = (const ushort4*)(y + (size_t)s0*H_DIM);
  const ushort4* y1 = (const ushort4*)(y + (size_t)s1*H_DIM);
  float4* o = (float4*)(out + (size_t)tok*H_DIM);
  ushort4 a = y0[threadIdx.x], b = y1[threadIdx.x];
  float4 r;
  r.x = bf2f(a.x)+bf2f(b.x);
  r.y = bf2f(a.y)+bf2f(b.y);
  r.z = bf2f(a.z)+bf2f(b.z);
  r.w = bf2f(a.w)+bf2f(b.w);
  o[threadIdx.x] = r;
}

extern "C" void kernel_launch(void* const* d_in, const int* in_sizes, int n_in,
                              void* d_out, int out_size, void* d_ws, size_t ws_size,
                              hipStream_t stream) {
  const float* x  = (const float*)d_in[0];
  const float* Wg = (const float*)d_in[1];
  const float* bg = (const float*)d_in[2];
  const float* W1 = (const float*)d_in[3];
  const float* b1 = (const float*)d_in[4];
  const float* W2 = (const float*)d_in[5];
  const float* b2 = (const float*)d_in[6];
  float* out = (float*)d_out;
  char* ws = (char*)d_ws;

  int*   cnt      = (int*)  (ws + OFF_CNT);
  int*   idxp     = (int*)  (ws + OFF_IDX);
  int*   posp     = (int*)  (ws + OFF_POS);
  float* wvp      = (float*)(ws + OFF_WV);
  int*   slot_of  = (int*)  (ws + OFF_SLOT);
  float* w_of     = (float*)(ws + OFF_WOF);
  unsigned short* Xg  = (unsigned short*)(ws + OFF_XG);
  unsigned short* W1t = (unsigned short*)(ws + OFF_W1T);
  unsigned short* W2t = (unsigned short*)(ws + OFF_W2T);
  unsigned short* mid = (unsigned short*)(ws + OFF_MID);
  unsigned short* y   = (unsigned short*)(ws + OFF_Y);

  hipMemsetAsync(ws + OFF_CNT, 0, 32, stream);

  gate_kernel<<<T_TOK/4, 64, 0, stream>>>(x, Wg, bg, cnt, idxp, posp, wvp);
  route_gather_kernel<<<SLOTS, 256, 0, stream>>>(x, idxp, posp, wvp, cnt, Xg, w_of, slot_of);
  transconv2_kernel<<<dim3(16384), 256, 0, stream>>>(W1, W1t, W2, W2t);

  // GEMM1: 18 tile-bands x 8 col-bands = 144 chunks -> 18 rounds x 128 = 2304
  gemm128_kernel<0><<<dim3(2304), 256, 0, stream>>>(
      Xg, W1t, b1, mid, cnt, nullptr, FF_DIM, H_DIM, 3);
  // GEMM2: 18 tile-bands x 2 col-bands = 36 chunks -> 5 rounds x 128 = 640
  gemm128_kernel<1><<<dim3(640), 256, 0, stream>>>(
      mid, W2t, b2, y, cnt, w_of, H_DIM, FF_DIM, 1);

  combine_kernel<<<T_TOK, 256, 0, stream>>>(y, slot_of, out);
}

// Round 18
// 410.877 us; speedup vs baseline: 1.8645x; 1.0220x over previous
//
#include <hip/hip_runtime.h>
#include <hip/hip_bf16.h>
#include <math.h>

// ---- problem constants ----
#define T_TOK  4096      // B*S tokens
#define H_DIM  1024
#define E_NUM  8
#define FF_DIM 4096
#define KSEL   2
#define SLOTS  (T_TOK*KSEL)     // 8192
#define SLOTS_PAD (SLOTS + 256)
#define BM 128
#define MAXTILES 72             // 128-row tiles (18 bands of 4)

typedef __attribute__((ext_vector_type(8))) short s16x8;
typedef __attribute__((ext_vector_type(8))) unsigned short u16x8;
typedef __attribute__((ext_vector_type(4))) float f32x4;

typedef __attribute__((address_space(1))) const void global_cvoid;
typedef __attribute__((address_space(3))) void lds_void;

__device__ __forceinline__ unsigned short f2bf(float f){
  unsigned int u = __float_as_uint(f);
  u += 0x7fffu + ((u>>16)&1u);
  return (unsigned short)(u>>16);
}
__device__ __forceinline__ float bf2f(unsigned short h){
  return __uint_as_float(((unsigned int)h)<<16);
}

// ---- workspace layout ----
static constexpr size_t OFF_CNT   = 0;                  // 8 ints
static constexpr size_t OFF_IDX   = 1280;               // [T][2] int
static constexpr size_t OFF_POS   = OFF_IDX  + 32768;
static constexpr size_t OFF_WV    = OFF_POS  + 32768;
static constexpr size_t OFF_SLOT  = OFF_WV   + 32768;   // [T][2] int
static constexpr size_t OFF_WOF   = OFF_SLOT + 32768;   // [SLOTS] float
static constexpr size_t OFF_XG    = OFF_WOF  + 32768;                       // [SLOTS_PAD][H] bf16
static constexpr size_t OFF_W1T   = OFF_XG  + (size_t)SLOTS_PAD*H_DIM*2;    // [E][FF][H] bf16
static constexpr size_t OFF_W2T   = OFF_W1T + (size_t)E_NUM*H_DIM*FF_DIM*2; // [E][H][FF] bf16
static constexpr size_t OFF_MID   = OFF_W2T + (size_t)E_NUM*H_DIM*FF_DIM*2; // [SLOTS_PAD][FF] bf16
static constexpr size_t OFF_Y     = OFF_MID + (size_t)SLOTS_PAD*FF_DIM*2;   // [SLOTS][H] bf16

// ---- prep: gate (blocks 0..255, 4 waves x 4 tokens each) + W1/W2
// transpose-convert (blocks 256..16639). Gate blocks first -> they fill CUs
// immediately and hide under the ~67 us BW-bound weight conversion. ----
__global__ __launch_bounds__(256) void prep_kernel(
    const float* __restrict__ W1, unsigned short* __restrict__ W1t,
    const float* __restrict__ W2, unsigned short* __restrict__ W2t,
    const float* __restrict__ x, const float* __restrict__ Wg,
    const float* __restrict__ bg, int* __restrict__ cnt,
    int* __restrict__ idxp, int* __restrict__ posp, float* __restrict__ wvp)
{
  int id = blockIdx.x;
  if (id < 256){
    // ---- gate: wave wv handles tokens (id*4+wv)*4 .. +4 ----
    int lane = threadIdx.x & 63;
    int wv = threadIdx.x >> 6;
    for (int tt=0; tt<4; ++tt){
      int t = (id*4 + wv)*4 + tt;
      const float* xr = x + (size_t)t*H_DIM;
      float acc[E_NUM];
      #pragma unroll
      for (int e=0;e<E_NUM;e++) acc[e]=0.f;
      for (int i=0;i<H_DIM/64;i++){
        int h = i*64 + lane;
        float xv = xr[h];
        const float* wr_ = Wg + (size_t)h*E_NUM;
        #pragma unroll
        for (int e=0;e<E_NUM;e++) acc[e] += xv*wr_[e];
      }
      #pragma unroll
      for (int e=0;e<E_NUM;e++){
        #pragma unroll
        for (int off=32; off>0; off>>=1) acc[e] += __shfl_xor(acc[e], off);
      }
      if (lane==0){
        float l[E_NUM];
        #pragma unroll
        for (int e=0;e<E_NUM;e++) l[e] = acc[e] + bg[e];
        int i0 = 0;
        #pragma unroll
        for (int e=1;e<E_NUM;e++) if (l[e] > l[i0]) i0 = e;
        int i1 = (i0==0)?1:0;
        #pragma unroll
        for (int e=0;e<E_NUM;e++) if (e!=i0 && l[e] > l[i1]) i1 = e;
        float p1 = expf(l[i1]-l[i0]);
        float s  = 1.f + p1;
        float w0 = 1.f/s, w1 = p1/s;
        int pos0 = atomicAdd(&cnt[i0],1);
        int pos1 = atomicAdd(&cnt[i1],1);
        idxp[t*2]=i0; idxp[t*2+1]=i1;
        posp[t*2]=pos0; posp[t*2+1]=pos1;
        wvp[t*2]=w0; wvp[t*2+1]=w1;
      }
    }
    return;
  }
  // ---- transconv ----
  __shared__ float tile[64][65];
  int id2 = id - 256;
  const float* in; unsigned short* out; int R, C, cx, cy, e;
  if (id2 < 8192){           // W1: R=1024(H), C=4096(FF)
    e = id2 >> 10; int rem = id2 & 1023;
    cx = rem & 63; cy = rem >> 6;
    R = H_DIM; C = FF_DIM; in = W1; out = W1t;
  } else {                   // W2: R=4096(FF), C=1024(H)
    int id3 = id2 - 8192;
    e = id3 >> 10; int rem = id3 & 1023;
    cx = rem & 15; cy = rem >> 4;
    R = FF_DIM; C = H_DIM; in = W2; out = W2t;
  }
  const float* inp = in + (size_t)e*R*C;
  unsigned short* op = out + (size_t)e*R*C;
  int c0 = cx*64, r0 = cy*64;
  int tx = threadIdx.x & 15, ty = threadIdx.x >> 4;
  #pragma unroll
  for (int i=0;i<4;i++){
    int r = i*16 + ty;
    float4 v = *(const float4*)(inp + (size_t)(r0+r)*C + c0 + tx*4);
    tile[r][tx*4+0]=v.x; tile[r][tx*4+1]=v.y; tile[r][tx*4+2]=v.z; tile[r][tx*4+3]=v.w;
  }
  __syncthreads();
  int wx = threadIdx.x & 7;
  int wcl = threadIdx.x >> 3;
  #pragma unroll
  for (int i=0;i<2;i++){
    int c = i*32 + wcl;
    u16x8 o;
    #pragma unroll
    for (int j=0;j<8;j++) o[j] = f2bf(tile[wx*8+j][c]);
    *(u16x8*)(op + (size_t)(c0+c)*R + r0 + wx*8) = o;
  }
}

// ---- route + gather fused (r17-validated) ----
__global__ __launch_bounds__(256) void route_gather_kernel(
    const float* __restrict__ x, const int* __restrict__ idxp,
    const int* __restrict__ posp, const float* __restrict__ wvp,
    const int* __restrict__ cnt,
    unsigned short* __restrict__ Xg, float* __restrict__ w_of,
    int* __restrict__ slot_of)
{
  int b = blockIdx.x;            // 0..SLOTS-1 : (token t, choice k)
  int t = b>>1;
  int e = idxp[b];
  int off = 0;
  #pragma unroll
  for (int i=0;i<E_NUM;i++) off += (i<e) ? cnt[i] : 0;
  int slot = off + posp[b];
  const float4* src = (const float4*)(x + (size_t)t*H_DIM);
  float4 v = src[threadIdx.x];
  ushort4 o;
  o.x=f2bf(v.x); o.y=f2bf(v.y); o.z=f2bf(v.z); o.w=f2bf(v.w);
  ((ushort4*)(Xg + (size_t)slot*H_DIM))[threadIdx.x] = o;
  if (threadIdx.x == 0){
    w_of[slot] = wvp[b];
    slot_of[b] = slot;
  }
}

#define GLDS(g, l) __builtin_amdgcn_global_load_lds((global_cvoid*)(g), (lds_void*)(l), 16, 0, 0)

// ==== grouped GEMM (r8/r16 core, frozen): 128x128, BK=32, 256 thr, dbuf,
// depth-2 counted vmcnt(4), 2-way-max swizzle, chunked XCD mapping,
// launch_bounds(256,4) (r15: (256,5) spilled acc -> 2x regression).
// Tile list computed IN-KERNEL from cnt. LDS-BW arithmetic (r17): this
// geometry runs ~102 B/cy/CU vs ~85-128 ceiling -> LDS-pipe-bound; 0
// conflicts. MODE 0: tanh-gelu -> mid. MODE 1: gate-scale -> y. ====
template<int MODE>
__global__ __launch_bounds__(256, 4) void gemm128_kernel(
    const unsigned short* __restrict__ A,    // [slots][K]
    const unsigned short* __restrict__ Bt,   // [E][N][K]
    const float* __restrict__ bias,          // [E][N]
    unsigned short* __restrict__ Out,        // [slots][N]
    const int* __restrict__ cnt,
    const float* __restrict__ w_of,
    int N, int K, int cpcs)                  // cpcs: log2(col-bands)
{
  // chunked mapping: L -> (xcd, slot) -> (chunk, within) -> (tile, col)
  int L = blockIdx.x;
  int xcd = L & 7;
  int slot = L >> 3;
  int within = slot & 15;
  int chunk = ((slot >> 4) << 3) + xcd;
  int tb = chunk >> cpcs;
  int cb = chunk & ((1<<cpcs)-1);
  int tile_id = tb*4 + (within & 3);
  int col0 = (cb*4 + (within >> 2)) << 7;

  // resolve (expert, tile-in-expert) from cnt prefix (uniform 8-iter loop)
  int e=0, row0=0, nv=0, acc_t=0, o=0, found=0;
  #pragma unroll
  for (int i=0;i<E_NUM;i++){
    int c = cnt[i];
    int nt = (c + BM-1) >> 7;
    if (!found && tile_id < acc_t + nt){
      int mt = tile_id - acc_t;
      e = i; row0 = o + mt*BM; nv = c - mt*BM; found = 1;
    }
    acc_t += nt; o += c;
  }
  if (!found) return;
  int nvalid = nv > BM ? BM : nv;
  const unsigned short* Be = Bt + (size_t)e*N*K;

  __shared__ unsigned short As[2][128*32];
  __shared__ unsigned short Bs[2][128*32];
  char* asb = (char*)&As[0][0];
  char* bsb = (char*)&Bs[0][0];

  int t = threadIdx.x;
  int wid = t>>6, lane = t&63;
  int wr = (wid>>1)*64, wc = (wid&1)*64;
  int fr = lane&15, fq = lane>>4;

  // staging: thread t -> row t>>2 (+64), phys chunk t&3;
  // source logical chunk scl = (phys - (row>>1))&3 (inverse of read swizzle)
  int srow = t>>2;
  int scl  = ((t&3) - ((t>>3)&3)) & 3;
  int sdst = wid*1024;

  const unsigned short* pA0 = A  + (size_t)(row0 + srow)*K      + scl*8;
  const unsigned short* pA1 = A  + (size_t)(row0 + 64 + srow)*K + scl*8;
  const unsigned short* pB0 = Be + (size_t)(col0 + srow)*K      + scl*8;
  const unsigned short* pB1 = Be + (size_t)(col0 + 64 + srow)*K + scl*8;

  auto stage = [&](int buf, int kelem){
    GLDS(pA0 + kelem, asb + buf*8192 + sdst);
    GLDS(pA1 + kelem, asb + buf*8192 + 4096 + sdst);
    GLDS(pB0 + kelem, bsb + buf*8192 + sdst);
    GLDS(pB1 + kelem, bsb + buf*8192 + 4096 + sdst);
  };

  int rd_sw = ((fq + ((fr>>1)&3)) & 3) << 4;

  f32x4 acc[4][4];
  #pragma unroll
  for (int i=0;i<4;i++)
    #pragma unroll
    for (int j=0;j<4;j++) acc[i][j] = (f32x4){0.f,0.f,0.f,0.f};

  int NT = K >> 5;
  stage(0, 0);
  stage(1, 32);
  for (int kt=0; kt<NT; ++kt){
    int cur = kt&1;
    if (kt+1 < NT) asm volatile("s_waitcnt vmcnt(4)" ::: "memory");
    else           asm volatile("s_waitcnt vmcnt(0)" ::: "memory");
    __builtin_amdgcn_s_barrier();
    asm volatile("" ::: "memory");

    s16x8 af[4], bfr[4];
    #pragma unroll
    for (int i=0;i<4;i++){
      af[i]  = *(const s16x8*)(asb + cur*8192 + (wr + i*16 + fr)*64 + rd_sw);
      bfr[i] = *(const s16x8*)(bsb + cur*8192 + (wc + i*16 + fr)*64 + rd_sw);
    }
    #pragma unroll
    for (int i=0;i<4;i++)
      #pragma unroll
      for (int j=0;j<4;j++)
        acc[i][j] = __builtin_amdgcn_mfma_f32_16x16x32_bf16(af[i], bfr[j], acc[i][j], 0,0,0);

    asm volatile("s_waitcnt lgkmcnt(0)" ::: "memory");
    __builtin_amdgcn_s_barrier();
    asm volatile("" ::: "memory");
    if (kt+2 < NT) stage(cur, (kt+2)*32);
  }

  // epilogue: C/D layout col=lane&15, row=(lane>>4)*4+reg. Bias hoisted.
  float bias_v[4];
  #pragma unroll
  for (int j=0;j<4;j++) bias_v[j] = bias[(size_t)e*N + col0 + wc + j*16 + fr];
  #pragma unroll
  for (int i=0;i<4;i++){
    #pragma unroll
    for (int r=0;r<4;r++){
      int lrow = wr + i*16 + fq*4 + r;
      if (lrow < nvalid){
        int grow = row0 + lrow;
        float scale = (MODE==1) ? w_of[grow] : 0.f;
        #pragma unroll
        for (int j=0;j<4;j++){
          int col = col0 + wc + j*16 + fr;
          float v = acc[i][j][r] + bias_v[j];
          if (MODE==0){
            // gelu, tanh form: v - v/(e^{2u}+1), u = 0.79788456(v + 0.044715 v^3)
            float u = v*(0.7978845608f + 0.0356774081f*v*v);
            float z = __expf(2.f*u);
            v = v - __fdividef(v, z + 1.f);
          } else {
            v *= scale;
          }
          Out[(size_t)grow*N + col] = f2bf(v);
        }
      }
    }
  }
}

// ---- combine: out[t] = y[slot0] + y[slot1] ----
__global__ __launch_bounds__(256) void combine_kernel(
    const unsigned short* __restrict__ y, const int* __restrict__ slot_of,
    float* __restrict__ out)
{
  int tok = blockIdx.x;
  int s0 = slot_of[tok*2], s1 = slot_of[tok*2+1];
  const ushort4* y0 = (const ushort4*)(y + (size_t)s0*H_DIM);
  const ushort4* y1 = (const ushort4*)(y + (size_t)s1*H_DIM);
  float4* o = (float4*)(out + (size_t)tok*H_DIM);
  ushort4 a = y0[threadIdx.x], b = y1[threadIdx.x];
  float4 r;
  r.x = bf2f(a.x)+bf2f(b.x);
  r.y = bf2f(a.y)+bf2f(b.y);
  r.z = bf2f(a.z)+bf2f(b.z);
  r.w = bf2f(a.w)+bf2f(b.w);
  o[threadIdx.x] = r;
}

extern "C" void kernel_launch(void* const* d_in, const int* in_sizes, int n_in,
                              void* d_out, int out_size, void* d_ws, size_t ws_size,
                              hipStream_t stream) {
  const float* x  = (const float*)d_in[0];
  const float* Wg = (const float*)d_in[1];
  const float* bg = (const float*)d_in[2];
  const float* W1 = (const float*)d_in[3];
  const float* b1 = (const float*)d_in[4];
  const float* W2 = (const float*)d_in[5];
  const float* b2 = (const float*)d_in[6];
  float* out = (float*)d_out;
  char* ws = (char*)d_ws;

  int*   cnt      = (int*)  (ws + OFF_CNT);
  int*   idxp     = (int*)  (ws + OFF_IDX);
  int*   posp     = (int*)  (ws + OFF_POS);
  float* wvp      = (float*)(ws + OFF_WV);
  int*   slot_of  = (int*)  (ws + OFF_SLOT);
  float* w_of     = (float*)(ws + OFF_WOF);
  unsigned short* Xg  = (unsigned short*)(ws + OFF_XG);
  unsigned short* W1t = (unsigned short*)(ws + OFF_W1T);
  unsigned short* W2t = (unsigned short*)(ws + OFF_W2T);
  unsigned short* mid = (unsigned short*)(ws + OFF_MID);
  unsigned short* y   = (unsigned short*)(ws + OFF_Y);

  hipMemsetAsync(ws + OFF_CNT, 0, 32, stream);

  // prep: gate (256 blocks, first) + W1/W2 transconv (16384 blocks)
  prep_kernel<<<dim3(16640), 256, 0, stream>>>(
      W1, W1t, W2, W2t, x, Wg, bg, cnt, idxp, posp, wvp);
  route_gather_kernel<<<SLOTS, 256, 0, stream>>>(x, idxp, posp, wvp, cnt, Xg, w_of, slot_of);

  // GEMM1: 18 tile-bands x 8 col-bands = 144 chunks -> 18 rounds x 128 = 2304
  gemm128_kernel<0><<<dim3(2304), 256, 0, stream>>>(
      Xg, W1t, b1, mid, cnt, nullptr, FF_DIM, H_DIM, 3);
  // GEMM2: 18 tile-bands x 2 col-bands = 36 chunks -> 5 rounds x 128 = 640
  gemm128_kernel<1><<<dim3(640), 256, 0, stream>>>(
      mid, W2t, b2, y, cnt, w_of, H_DIM, FF_DIM, 1);

  combine_kernel<<<T_TOK, 256, 0, stream>>>(y, slot_of, out);
}

// Round 19
// 397.839 us; speedup vs baseline: 1.9256x; 1.0328x over previous
//
#include <hip/hip_runtime.h>
#include <hip/hip_bf16.h>
#include <math.h>

// ---- problem constants ----
#define T_TOK  4096      // B*S tokens
#define H_DIM  1024
#define E_NUM  8
#define FF_DIM 4096
#define KSEL   2
#define SLOTS  (T_TOK*KSEL)     // 8192
#define SLOTS_PAD (SLOTS + 256)
#define BM 128
#define MAXTILES 72             // 128-row tiles (18 bands of 4)

typedef __attribute__((ext_vector_type(8))) short s16x8;
typedef __attribute__((ext_vector_type(8))) unsigned short u16x8;
typedef __attribute__((ext_vector_type(4))) float f32x4;

typedef __attribute__((address_space(1))) const void global_cvoid;
typedef __attribute__((address_space(3))) void lds_void;

__device__ __forceinline__ unsigned short f2bf(float f){
  unsigned int u = __float_as_uint(f);
  u += 0x7fffu + ((u>>16)&1u);
  return (unsigned short)(u>>16);
}
__device__ __forceinline__ float bf2f(unsigned short h){
  return __uint_as_float(((unsigned int)h)<<16);
}

// ---- workspace layout ----
static constexpr size_t OFF_CNT   = 0;                  // 8 ints
static constexpr size_t OFF_IDX   = 1280;               // [T][2] int
static constexpr size_t OFF_POS   = OFF_IDX  + 32768;
static constexpr size_t OFF_WV    = OFF_POS  + 32768;
static constexpr size_t OFF_SLOT  = OFF_WV   + 32768;   // [T][2] int
static constexpr size_t OFF_WOF   = OFF_SLOT + 32768;   // [SLOTS] float
static constexpr size_t OFF_XG    = OFF_WOF  + 32768;                       // [SLOTS_PAD][H] bf16
static constexpr size_t OFF_W1T   = OFF_XG  + (size_t)SLOTS_PAD*H_DIM*2;    // [E][FF][H] bf16
static constexpr size_t OFF_W2T   = OFF_W1T + (size_t)E_NUM*H_DIM*FF_DIM*2; // [E][H][FF] bf16
static constexpr size_t OFF_MID   = OFF_W2T + (size_t)E_NUM*H_DIM*FF_DIM*2; // [SLOTS_PAD][FF] bf16
static constexpr size_t OFF_Y     = OFF_MID + (size_t)SLOTS_PAD*FF_DIM*2;   // [SLOTS][H] bf16

// ---- strip transpose-convert: 64 rows x 256 cols (4 tiles), single LDS
// buffer, next-tile loads issued EARLY (hidden under LDS write/read/store). ----
__device__ __forceinline__ void transconv_strip(
    const float* __restrict__ inp, unsigned short* __restrict__ op,
    int R, int C, int r0, int c0base, char* smem)
{
  float (*tile)[65] = (float(*)[65])smem;
  int tx = threadIdx.x & 15, ty = threadIdx.x >> 4;
  int wx = threadIdx.x & 7,  wcl = threadIdx.x >> 3;
  float4 cur[4], nxt[4];
  #pragma unroll
  for (int i=0;i<4;i++)
    cur[i] = *(const float4*)(inp + (size_t)(r0+i*16+ty)*C + c0base + tx*4);
  for (int it=0; it<4; ++it){
    int c0 = c0base + it*64;
    if (it < 3){
      #pragma unroll
      for (int i=0;i<4;i++)
        nxt[i] = *(const float4*)(inp + (size_t)(r0+i*16+ty)*C + c0 + 64 + tx*4);
    }
    #pragma unroll
    for (int i=0;i<4;i++){
      int r = i*16 + ty;
      tile[r][tx*4+0]=cur[i].x; tile[r][tx*4+1]=cur[i].y;
      tile[r][tx*4+2]=cur[i].z; tile[r][tx*4+3]=cur[i].w;
    }
    __syncthreads();
    #pragma unroll
    for (int i=0;i<2;i++){
      int c = i*32 + wcl;
      u16x8 o;
      #pragma unroll
      for (int j=0;j<8;j++) o[j] = f2bf(tile[wx*8+j][c]);
      *(u16x8*)(op + (size_t)(c0+c)*R + r0 + wx*8) = o;
    }
    __syncthreads();
    if (it < 3){
      #pragma unroll
      for (int i=0;i<4;i++) cur[i] = nxt[i];
    }
  }
}

// ---- prep: gate (blocks 0..255) + W1 strip-transconv (blocks 256..2303) ----
__global__ __launch_bounds__(256) void prep_kernel(
    const float* __restrict__ W1, unsigned short* __restrict__ W1t,
    const float* __restrict__ x, const float* __restrict__ Wg,
    const float* __restrict__ bg, int* __restrict__ cnt,
    int* __restrict__ idxp, int* __restrict__ posp, float* __restrict__ wvp)
{
  __shared__ char smem[16768];
  int id = blockIdx.x;
  if (id < 256){
    // gate: wave wv handles tokens (id*4+wv)*4 .. +4
    int lane = threadIdx.x & 63;
    int wv = threadIdx.x >> 6;
    for (int tt=0; tt<4; ++tt){
      int t = (id*4 + wv)*4 + tt;
      const float* xr = x + (size_t)t*H_DIM;
      float acc[E_NUM];
      #pragma unroll
      for (int e=0;e<E_NUM;e++) acc[e]=0.f;
      for (int i=0;i<H_DIM/64;i++){
        int h = i*64 + lane;
        float xv = xr[h];
        const float* wr_ = Wg + (size_t)h*E_NUM;
        #pragma unroll
        for (int e=0;e<E_NUM;e++) acc[e] += xv*wr_[e];
      }
      #pragma unroll
      for (int e=0;e<E_NUM;e++){
        #pragma unroll
        for (int off=32; off>0; off>>=1) acc[e] += __shfl_xor(acc[e], off);
      }
      if (lane==0){
        float l[E_NUM];
        #pragma unroll
        for (int e=0;e<E_NUM;e++) l[e] = acc[e] + bg[e];
        int i0 = 0;
        #pragma unroll
        for (int e=1;e<E_NUM;e++) if (l[e] > l[i0]) i0 = e;
        int i1 = (i0==0)?1:0;
        #pragma unroll
        for (int e=0;e<E_NUM;e++) if (e!=i0 && l[e] > l[i1]) i1 = e;
        float p1 = expf(l[i1]-l[i0]);
        float s  = 1.f + p1;
        float w0 = 1.f/s, w1 = p1/s;
        int pos0 = atomicAdd(&cnt[i0],1);
        int pos1 = atomicAdd(&cnt[i1],1);
        idxp[t*2]=i0; idxp[t*2+1]=i1;
        posp[t*2]=pos0; posp[t*2+1]=pos1;
        wvp[t*2]=w0; wvp[t*2+1]=w1;
      }
    }
    return;
  }
  // W1 strips: R=1024(H), C=4096(FF); 16 r-strips x 16 c-strips per expert
  int s = id - 256;            // 0..2047
  int e = s >> 8;
  int rem = s & 255;
  int rs = rem >> 4, cs = rem & 15;
  transconv_strip(W1 + (size_t)e*H_DIM*FF_DIM, W1t + (size_t)e*H_DIM*FF_DIM,
                  H_DIM, FF_DIM, rs*64, cs*256, smem);
}

// ---- route + gather fused (r17-validated) ----
__global__ __launch_bounds__(256) void route_gather_kernel(
    const float* __restrict__ x, const int* __restrict__ idxp,
    const int* __restrict__ posp, const float* __restrict__ wvp,
    const int* __restrict__ cnt,
    unsigned short* __restrict__ Xg, float* __restrict__ w_of,
    int* __restrict__ slot_of)
{
  int b = blockIdx.x;            // 0..SLOTS-1 : (token t, choice k)
  int t = b>>1;
  int e = idxp[b];
  int off = 0;
  #pragma unroll
  for (int i=0;i<E_NUM;i++) off += (i<e) ? cnt[i] : 0;
  int slot = off + posp[b];
  const float4* src = (const float4*)(x + (size_t)t*H_DIM);
  float4 v = src[threadIdx.x];
  ushort4 o;
  o.x=f2bf(v.x); o.y=f2bf(v.y); o.z=f2bf(v.z); o.w=f2bf(v.w);
  ((ushort4*)(Xg + (size_t)slot*H_DIM))[threadIdx.x] = o;
  if (threadIdx.x == 0){
    w_of[slot] = wvp[b];
    slot_of[b] = slot;
  }
}

#define GLDS(g, l) __builtin_amdgcn_global_load_lds((global_cvoid*)(g), (lds_void*)(l), 16, 0, 0)

// ==== grouped GEMM (r8/r16 core, frozen) + (MODE 0 only) 2048 leading
// W2-strip-transconv blocks overlapped under the LDS-bound GEMM (HBM was
// idle at 0.8 TB/s during GEMM1 -> W2 conversion hides there).
// 128x128, BK=32, 256 thr, dbuf, depth-2 counted vmcnt(4), 2-way-max
// swizzle, chunked XCD mapping, launch_bounds(256,4) (r15: don't starve acc).
// MODE 0: tanh-gelu -> mid. MODE 1: gate-scale -> y. ====
template<int MODE>
__global__ __launch_bounds__(256, 4) void gemm128_kernel(
    const unsigned short* __restrict__ A,    // [slots][K]
    const unsigned short* __restrict__ Bt,   // [E][N][K]
    const float* __restrict__ bias,          // [E][N]
    unsigned short* __restrict__ Out,        // [slots][N]
    const int* __restrict__ cnt,
    const float* __restrict__ w_of,
    const float* __restrict__ Wsrc,          // MODE0: W2 [E][FF][H]
    unsigned short* __restrict__ Wdst,       // MODE0: W2t [E][H][FF]
    int N, int K, int cpcs)                  // cpcs: log2(col-bands)
{
  __shared__ char smem[32768];
  int L = blockIdx.x;
  if (MODE==0 && L < 2048){
    // W2 strips: R=4096(FF), C=1024(H); 64 r-strips x 4 c-strips per expert
    int e = L >> 8;
    int rem = L & 255;
    int rs = rem >> 2, cs = rem & 3;
    transconv_strip(Wsrc + (size_t)e*H_DIM*FF_DIM, Wdst + (size_t)e*H_DIM*FF_DIM,
                    FF_DIM, H_DIM, rs*64, cs*256, smem);
    return;
  }
  int L2 = (MODE==0) ? (L - 2048) : L;

  // chunked mapping: L2 -> (xcd, slot) -> (chunk, within) -> (tile, col)
  int xcd = L2 & 7;
  int slot = L2 >> 3;
  int within = slot & 15;
  int chunk = ((slot >> 4) << 3) + xcd;
  int tb = chunk >> cpcs;
  int cb = chunk & ((1<<cpcs)-1);
  int tile_id = tb*4 + (within & 3);
  int col0 = (cb*4 + (within >> 2)) << 7;

  // resolve (expert, tile-in-expert) from cnt prefix (uniform 8-iter loop)
  int e=0, row0=0, nv=0, acc_t=0, o=0, found=0;
  #pragma unroll
  for (int i=0;i<E_NUM;i++){
    int c = cnt[i];
    int nt = (c + BM-1) >> 7;
    if (!found && tile_id < acc_t + nt){
      int mt = tile_id - acc_t;
      e = i; row0 = o + mt*BM; nv = c - mt*BM; found = 1;
    }
    acc_t += nt; o += c;
  }
  if (!found) return;
  int nvalid = nv > BM ? BM : nv;
  const unsigned short* Be = Bt + (size_t)e*N*K;

  char* asb = smem;            // [buf][128 rows][64 B] = 16 KB
  char* bsb = smem + 16384;

  int t = threadIdx.x;
  int wid = t>>6, lane = t&63;
  int wr = (wid>>1)*64, wc = (wid&1)*64;
  int fr = lane&15, fq = lane>>4;

  // staging: thread t -> row t>>2 (+64), phys chunk t&3;
  // source logical chunk scl = (phys - (row>>1))&3 (inverse of read swizzle)
  int srow = t>>2;
  int scl  = ((t&3) - ((t>>3)&3)) & 3;
  int sdst = wid*1024;

  const unsigned short* pA0 = A  + (size_t)(row0 + srow)*K      + scl*8;
  const unsigned short* pA1 = A  + (size_t)(row0 + 64 + srow)*K + scl*8;
  const unsigned short* pB0 = Be + (size_t)(col0 + srow)*K      + scl*8;
  const unsigned short* pB1 = Be + (size_t)(col0 + 64 + srow)*K + scl*8;

  auto stage = [&](int buf, int kelem){
    GLDS(pA0 + kelem, asb + buf*8192 + sdst);
    GLDS(pA1 + kelem, asb + buf*8192 + 4096 + sdst);
    GLDS(pB0 + kelem, bsb + buf*8192 + sdst);
    GLDS(pB1 + kelem, bsb + buf*8192 + 4096 + sdst);
  };

  int rd_sw = ((fq + ((fr>>1)&3)) & 3) << 4;

  f32x4 acc[4][4];
  #pragma unroll
  for (int i=0;i<4;i++)
    #pragma unroll
    for (int j=0;j<4;j++) acc[i][j] = (f32x4){0.f,0.f,0.f,0.f};

  int NT = K >> 5;
  stage(0, 0);
  stage(1, 32);
  for (int kt=0; kt<NT; ++kt){
    int cur = kt&1;
    if (kt+1 < NT) asm volatile("s_waitcnt vmcnt(4)" ::: "memory");
    else           asm volatile("s_waitcnt vmcnt(0)" ::: "memory");
    __builtin_amdgcn_s_barrier();
    asm volatile("" ::: "memory");

    s16x8 af[4], bfr[4];
    #pragma unroll
    for (int i=0;i<4;i++){
      af[i]  = *(const s16x8*)(asb + cur*8192 + (wr + i*16 + fr)*64 + rd_sw);
      bfr[i] = *(const s16x8*)(bsb + cur*8192 + (wc + i*16 + fr)*64 + rd_sw);
    }
    #pragma unroll
    for (int i=0;i<4;i++)
      #pragma unroll
      for (int j=0;j<4;j++)
        acc[i][j] = __builtin_amdgcn_mfma_f32_16x16x32_bf16(af[i], bfr[j], acc[i][j], 0,0,0);

    asm volatile("s_waitcnt lgkmcnt(0)" ::: "memory");
    __builtin_amdgcn_s_barrier();
    asm volatile("" ::: "memory");
    if (kt+2 < NT) stage(cur, (kt+2)*32);
  }

  // epilogue: C/D layout col=lane&15, row=(lane>>4)*4+reg. Bias hoisted.
  float bias_v[4];
  #pragma unroll
  for (int j=0;j<4;j++) bias_v[j] = bias[(size_t)e*N + col0 + wc + j*16 + fr];
  #pragma unroll
  for (int i=0;i<4;i++){
    #pragma unroll
    for (int r=0;r<4;r++){
      int lrow = wr + i*16 + fq*4 + r;
      if (lrow < nvalid){
        int grow = row0 + lrow;
        float scale = (MODE==1) ? w_of[grow] : 0.f;
        #pragma unroll
        for (int j=0;j<4;j++){
          int col = col0 + wc + j*16 + fr;
          float v = acc[i][j][r] + bias_v[j];
          if (MODE==0){
            // gelu, tanh form: v - v/(e^{2u}+1), u = 0.79788456(v + 0.044715 v^3)
            float u = v*(0.7978845608f + 0.0356774081f*v*v);
            float z = __expf(2.f*u);
            v = v - __fdividef(v, z + 1.f);
          } else {
            v *= scale;
          }
          Out[(size_t)grow*N + col] = f2bf(v);
        }
      }
    }
  }
}

// ---- combine: out[t] = y[slot0] + y[slot1] ----
__global__ __launch_bounds__(256) void combine_kernel(
    const unsigned short* __restrict__ y, const int* __restrict__ slot_of,
    float* __restrict__ out)
{
  int tok = blockIdx.x;
  int s0 = slot_of[tok*2], s1 = slot_of[tok*2+1];
  const ushort4* y0 = (const ushort4*)(y + (size_t)s0*H_DIM);
  const ushort4* y1 = (const ushort4*)(y + (size_t)s1*H_DIM);
  float4* o = (float4*)(out + (size_t)tok*H_DIM);
  ushort4 a = y0[threadIdx.x], b = y1[threadIdx.x];
  float4 r;
  r.x = bf2f(a.x)+bf2f(b.x);
  r.y = bf2f(a.y)+bf2f(b.y);
  r.z = bf2f(a.z)+bf2f(b.z);
  r.w = bf2f(a.w)+bf2f(b.w);
  o[threadIdx.x] = r;
}

extern "C" void kernel_launch(void* const* d_in, const int* in_sizes, int n_in,
                              void* d_out, int out_size, void* d_ws, size_t ws_size,
                              hipStream_t stream) {
  const float* x  = (const float*)d_in[0];
  const float* Wg = (const float*)d_in[1];
  const float* bg = (const float*)d_in[2];
  const float* W1 = (const float*)d_in[3];
  const float* b1 = (const float*)d_in[4];
  const float* W2 = (const float*)d_in[5];
  const float* b2 = (const float*)d_in[6];
  float* out = (float*)d_out;
  char* ws = (char*)d_ws;

  int*   cnt      = (int*)  (ws + OFF_CNT);
  int*   idxp     = (int*)  (ws + OFF_IDX);
  int*   posp     = (int*)  (ws + OFF_POS);
  float* wvp      = (float*)(ws + OFF_WV);
  int*   slot_of  = (int*)  (ws + OFF_SLOT);
  float* w_of     = (float*)(ws + OFF_WOF);
  unsigned short* Xg  = (unsigned short*)(ws + OFF_XG);
  unsigned short* W1t = (unsigned short*)(ws + OFF_W1T);
  unsigned short* W2t = (unsigned short*)(ws + OFF_W2T);
  unsigned short* mid = (unsigned short*)(ws + OFF_MID);
  unsigned short* y   = (unsigned short*)(ws + OFF_Y);

  hipMemsetAsync(ws + OFF_CNT, 0, 32, stream);

  // prep: gate (256) + W1 strip-transconv (2048)
  prep_kernel<<<dim3(2304), 256, 0, stream>>>(
      W1, W1t, x, Wg, bg, cnt, idxp, posp, wvp);
  route_gather_kernel<<<SLOTS, 256, 0, stream>>>(x, idxp, posp, wvp, cnt, Xg, w_of, slot_of);

  // GEMM1 launch: 2048 W2 strip-transconv blocks + 2304 GEMM blocks
  gemm128_kernel<0><<<dim3(2048 + 2304), 256, 0, stream>>>(
      Xg, W1t, b1, mid, cnt, nullptr, W2, W2t, FF_DIM, H_DIM, 3);
  // GEMM2: 18 tile-bands x 2 col-bands = 36 chunks -> 5 rounds x 128 = 640
  gemm128_kernel<1><<<dim3(640), 256, 0, stream>>>(
      mid, W2t, b2, y, cnt, w_of, nullptr, nullptr, H_DIM, FF_DIM, 1);

  combine_kernel<<<T_TOK, 256, 0, stream>>>(y, slot_of, out);
}

// Round 20
// 388.054 us; speedup vs baseline: 1.9741x; 1.0252x over previous
//
#include <hip/hip_runtime.h>
#include <hip/hip_bf16.h>
#include <math.h>

// ---- problem constants ----
#define T_TOK  4096      // B*S tokens
#define H_DIM  1024
#define E_NUM  8
#define FF_DIM 4096
#define KSEL   2
#define SLOTS  (T_TOK*KSEL)     // 8192
#define SLOTS_PAD (SLOTS + 256)
#define BM 128
#define MAXTILES 72             // 128-row tiles (18 bands of 4)

typedef __attribute__((ext_vector_type(8))) short s16x8;
typedef __attribute__((ext_vector_type(8))) unsigned short u16x8;
typedef __attribute__((ext_vector_type(4))) float f32x4;

typedef __attribute__((address_space(1))) const void global_cvoid;
typedef __attribute__((address_space(3))) void lds_void;

__device__ __forceinline__ unsigned short f2bf(float f){
  unsigned int u = __float_as_uint(f);
  u += 0x7fffu + ((u>>16)&1u);
  return (unsigned short)(u>>16);
}
__device__ __forceinline__ float bf2f(unsigned short h){
  return __uint_as_float(((unsigned int)h)<<16);
}

// ---- workspace layout ----
static constexpr size_t OFF_CNT   = 0;                  // 8 ints
static constexpr size_t OFF_IDX   = 1280;               // [T][2] int
static constexpr size_t OFF_POS   = OFF_IDX  + 32768;
static constexpr size_t OFF_WV    = OFF_POS  + 32768;
static constexpr size_t OFF_SLOT  = OFF_WV   + 32768;   // [T][2] int
static constexpr size_t OFF_WOF   = OFF_SLOT + 32768;   // [SLOTS] float
static constexpr size_t OFF_XG    = OFF_WOF  + 32768;                       // [SLOTS_PAD][H] bf16
static constexpr size_t OFF_W1T   = OFF_XG  + (size_t)SLOTS_PAD*H_DIM*2;    // [E][FF][H] bf16
static constexpr size_t OFF_W2T   = OFF_W1T + (size_t)E_NUM*H_DIM*FF_DIM*2; // [E][H][FF] bf16
static constexpr size_t OFF_MID   = OFF_W2T + (size_t)E_NUM*H_DIM*FF_DIM*2; // [SLOTS_PAD][FF] bf16
static constexpr size_t OFF_Y     = OFF_MID + (size_t)SLOTS_PAD*FF_DIM*2;   // [SLOTS][H] bf16

// ---- strip transpose-convert: 64 rows x 512 cols (8 tiles), DOUBLE-buffered
// LDS (one barrier per tile), next-tile loads issued before current stores. ----
__device__ __forceinline__ void transconv_strip8(
    const float* __restrict__ inp, unsigned short* __restrict__ op,
    int R, int C, int r0, int c0base, char* smem)
{
  float (*tile)[65] = (float(*)[65])smem;      // [2][64][65] floats
  int tx = threadIdx.x & 15, ty = threadIdx.x >> 4;
  int wx = threadIdx.x & 7,  wcl = threadIdx.x >> 3;
  float4 cur[4], nxt[4];
  #pragma unroll
  for (int i=0;i<4;i++)
    cur[i] = *(const float4*)(inp + (size_t)(r0+i*16+ty)*C + c0base + tx*4);
  for (int it=0; it<8; ++it){
    int c0 = c0base + it*64;
    float (*tb)[65] = tile + (it&1)*64;
    if (it < 7){
      #pragma unroll
      for (int i=0;i<4;i++)
        nxt[i] = *(const float4*)(inp + (size_t)(r0+i*16+ty)*C + c0 + 64 + tx*4);
    }
    #pragma unroll
    for (int i=0;i<4;i++){
      int r = i*16 + ty;
      tb[r][tx*4+0]=cur[i].x; tb[r][tx*4+1]=cur[i].y;
      tb[r][tx*4+2]=cur[i].z; tb[r][tx*4+3]=cur[i].w;
    }
    __syncthreads();
    #pragma unroll
    for (int i=0;i<2;i++){
      int c = i*32 + wcl;
      u16x8 o;
      #pragma unroll
      for (int j=0;j<8;j++) o[j] = f2bf(tb[wx*8+j][c]);
      *(u16x8*)(op + (size_t)(c0+c)*R + r0 + wx*8) = o;
    }
    #pragma unroll
    for (int i=0;i<4;i++) cur[i] = nxt[i];
    // no second barrier: next iteration writes the OTHER buffer; the barrier
    // above orders this iteration's reads against next-next overwrite.
    if (it < 7) __syncthreads();
  }
}

// ---- prep: gate (blocks 0..255) + W1 strip-transconv (blocks 256..1279) ----
__global__ __launch_bounds__(256) void prep_kernel(
    const float* __restrict__ W1, unsigned short* __restrict__ W1t,
    const float* __restrict__ x, const float* __restrict__ Wg,
    const float* __restrict__ bg, int* __restrict__ cnt,
    int* __restrict__ idxp, int* __restrict__ posp, float* __restrict__ wvp)
{
  __shared__ char smem[33536];   // 2 x 64 x 65 floats
  int id = blockIdx.x;
  if (id < 256){
    // gate: wave wv handles tokens (id*4+wv)*4 .. +4
    int lane = threadIdx.x & 63;
    int wv = threadIdx.x >> 6;
    for (int tt=0; tt<4; ++tt){
      int t = (id*4 + wv)*4 + tt;
      const float* xr = x + (size_t)t*H_DIM;
      float acc[E_NUM];
      #pragma unroll
      for (int e=0;e<E_NUM;e++) acc[e]=0.f;
      for (int i=0;i<H_DIM/64;i++){
        int h = i*64 + lane;
        float xv = xr[h];
        const float* wr_ = Wg + (size_t)h*E_NUM;
        #pragma unroll
        for (int e=0;e<E_NUM;e++) acc[e] += xv*wr_[e];
      }
      #pragma unroll
      for (int e=0;e<E_NUM;e++){
        #pragma unroll
        for (int off=32; off>0; off>>=1) acc[e] += __shfl_xor(acc[e], off);
      }
      if (lane==0){
        float l[E_NUM];
        #pragma unroll
        for (int e=0;e<E_NUM;e++) l[e] = acc[e] + bg[e];
        int i0 = 0;
        #pragma unroll
        for (int e=1;e<E_NUM;e++) if (l[e] > l[i0]) i0 = e;
        int i1 = (i0==0)?1:0;
        #pragma unroll
        for (int e=0;e<E_NUM;e++) if (e!=i0 && l[e] > l[i1]) i1 = e;
        float p1 = expf(l[i1]-l[i0]);
        float s  = 1.f + p1;
        float w0 = 1.f/s, w1 = p1/s;
        int pos0 = atomicAdd(&cnt[i0],1);
        int pos1 = atomicAdd(&cnt[i1],1);
        idxp[t*2]=i0; idxp[t*2+1]=i1;
        posp[t*2]=pos0; posp[t*2+1]=pos1;
        wvp[t*2]=w0; wvp[t*2+1]=w1;
      }
    }
    return;
  }
  // W1 strips: R=1024(H), C=4096(FF); per expert: 16 r-strips x 8 c-strips
  int s = id - 256;            // 0..1023
  int e = s >> 7;
  int rem = s & 127;
  int rs = rem >> 3, cs = rem & 7;
  transconv_strip8(W1 + (size_t)e*H_DIM*FF_DIM, W1t + (size_t)e*H_DIM*FF_DIM,
                   H_DIM, FF_DIM, rs*64, cs*512, smem);
}

// ---- route + gather fused; 8 slots per block ----
__global__ __launch_bounds__(256) void route_gather_kernel(
    const float* __restrict__ x, const int* __restrict__ idxp,
    const int* __restrict__ posp, const float* __restrict__ wvp,
    const int* __restrict__ cnt,
    unsigned short* __restrict__ Xg, float* __restrict__ w_of,
    int* __restrict__ slot_of)
{
  #pragma unroll
  for (int s=0; s<8; ++s){
    int b = blockIdx.x*8 + s;      // 0..SLOTS-1 : (token t, choice k)
    int t = b>>1;
    int e = idxp[b];
    int off = 0;
    #pragma unroll
    for (int i=0;i<E_NUM;i++) off += (i<e) ? cnt[i] : 0;
    int slot = off + posp[b];
    const float4* src = (const float4*)(x + (size_t)t*H_DIM);
    float4 v = src[threadIdx.x];
    ushort4 o;
    o.x=f2bf(v.x); o.y=f2bf(v.y); o.z=f2bf(v.z); o.w=f2bf(v.w);
    ((ushort4*)(Xg + (size_t)slot*H_DIM))[threadIdx.x] = o;
    if (threadIdx.x == 0){
      w_of[slot] = wvp[b];
      slot_of[b] = slot;
    }
  }
}

#define GLDS(g, l) __builtin_amdgcn_global_load_lds((global_cvoid*)(g), (lds_void*)(l), 16, 0, 0)

// ==== grouped GEMM (r8/r16 core, frozen) + (MODE 0 only) 1024 leading
// W2-strip-transconv blocks overlapped under the LDS-bound GEMM.
// 128x128, BK=32, 256 thr, dbuf, depth-2 counted vmcnt(4), 2-way-max
// swizzle, chunked XCD mapping, launch_bounds(256,4).
// MODE 0: tanh-gelu -> mid. MODE 1: gate-scale -> y. ====
template<int MODE>
__global__ __launch_bounds__(256, 4) void gemm128_kernel(
    const unsigned short* __restrict__ A,    // [slots][K]
    const unsigned short* __restrict__ Bt,   // [E][N][K]
    const float* __restrict__ bias,          // [E][N]
    unsigned short* __restrict__ Out,        // [slots][N]
    const int* __restrict__ cnt,
    const float* __restrict__ w_of,
    const float* __restrict__ Wsrc,          // MODE0: W2 [E][FF][H]
    unsigned short* __restrict__ Wdst,       // MODE0: W2t [E][H][FF]
    int N, int K, int cpcs)                  // cpcs: log2(col-bands)
{
  __shared__ char smem[33536];
  int L = blockIdx.x;
  if (MODE==0 && L < 1024){
    // W2 strips: R=4096(FF), C=1024(H); per expert: 64 r-strips x 2 c-strips
    int e = L >> 7;
    int rem = L & 127;
    int rs = rem >> 1, cs = rem & 1;
    transconv_strip8(Wsrc + (size_t)e*H_DIM*FF_DIM, Wdst + (size_t)e*H_DIM*FF_DIM,
                     FF_DIM, H_DIM, rs*64, cs*512, smem);
    return;
  }
  int L2 = (MODE==0) ? (L - 1024) : L;

  // chunked mapping: L2 -> (xcd, slot) -> (chunk, within) -> (tile, col)
  int xcd = L2 & 7;
  int slot = L2 >> 3;
  int within = slot & 15;
  int chunk = ((slot >> 4) << 3) + xcd;
  int tb = chunk >> cpcs;
  int cb = chunk & ((1<<cpcs)-1);
  int tile_id = tb*4 + (within & 3);
  int col0 = (cb*4 + (within >> 2)) << 7;

  // resolve (expert, tile-in-expert) from cnt prefix (uniform 8-iter loop)
  int e=0, row0=0, nv=0, acc_t=0, o=0, found=0;
  #pragma unroll
  for (int i=0;i<E_NUM;i++){
    int c = cnt[i];
    int nt = (c + BM-1) >> 7;
    if (!found && tile_id < acc_t + nt){
      int mt = tile_id - acc_t;
      e = i; row0 = o + mt*BM; nv = c - mt*BM; found = 1;
    }
    acc_t += nt; o += c;
  }
  if (!found) return;
  int nvalid = nv > BM ? BM : nv;
  const unsigned short* Be = Bt + (size_t)e*N*K;

  char* asb = smem;            // [buf][128 rows][64 B] = 16 KB
  char* bsb = smem + 16384;

  int t = threadIdx.x;
  int wid = t>>6, lane = t&63;
  int wr = (wid>>1)*64, wc = (wid&1)*64;
  int fr = lane&15, fq = lane>>4;

  // staging: thread t -> row t>>2 (+64), phys chunk t&3;
  // source logical chunk scl = (phys - (row>>1))&3 (inverse of read swizzle)
  int srow = t>>2;
  int scl  = ((t&3) - ((t>>3)&3)) & 3;
  int sdst = wid*1024;

  const unsigned short* pA0 = A  + (size_t)(row0 + srow)*K      + scl*8;
  const unsigned short* pA1 = A  + (size_t)(row0 + 64 + srow)*K + scl*8;
  const unsigned short* pB0 = Be + (size_t)(col0 + srow)*K      + scl*8;
  const unsigned short* pB1 = Be + (size_t)(col0 + 64 + srow)*K + scl*8;

  auto stage = [&](int buf, int kelem){
    GLDS(pA0 + kelem, asb + buf*8192 + sdst);
    GLDS(pA1 + kelem, asb + buf*8192 + 4096 + sdst);
    GLDS(pB0 + kelem, bsb + buf*8192 + sdst);
    GLDS(pB1 + kelem, bsb + buf*8192 + 4096 + sdst);
  };

  int rd_sw = ((fq + ((fr>>1)&3)) & 3) << 4;

  f32x4 acc[4][4];
  #pragma unroll
  for (int i=0;i<4;i++)
    #pragma unroll
    for (int j=0;j<4;j++) acc[i][j] = (f32x4){0.f,0.f,0.f,0.f};

  int NT = K >> 5;
  stage(0, 0);
  stage(1, 32);
  for (int kt=0; kt<NT; ++kt){
    int cur = kt&1;
    if (kt+1 < NT) asm volatile("s_waitcnt vmcnt(4)" ::: "memory");
    else           asm volatile("s_waitcnt vmcnt(0)" ::: "memory");
    __builtin_amdgcn_s_barrier();
    asm volatile("" ::: "memory");

    s16x8 af[4], bfr[4];
    #pragma unroll
    for (int i=0;i<4;i++){
      af[i]  = *(const s16x8*)(asb + cur*8192 + (wr + i*16 + fr)*64 + rd_sw);
      bfr[i] = *(const s16x8*)(bsb + cur*8192 + (wc + i*16 + fr)*64 + rd_sw);
    }
    #pragma unroll
    for (int i=0;i<4;i++)
      #pragma unroll
      for (int j=0;j<4;j++)
        acc[i][j] = __builtin_amdgcn_mfma_f32_16x16x32_bf16(af[i], bfr[j], acc[i][j], 0,0,0);

    asm volatile("s_waitcnt lgkmcnt(0)" ::: "memory");
    __builtin_amdgcn_s_barrier();
    asm volatile("" ::: "memory");
    if (kt+2 < NT) stage(cur, (kt+2)*32);
  }

  // epilogue: C/D layout col=lane&15, row=(lane>>4)*4+reg. Bias hoisted.
  float bias_v[4];
  #pragma unroll
  for (int j=0;j<4;j++) bias_v[j] = bias[(size_t)e*N + col0 + wc + j*16 + fr];
  #pragma unroll
  for (int i=0;i<4;i++){
    #pragma unroll
    for (int r=0;r<4;r++){
      int lrow = wr + i*16 + fq*4 + r;
      if (lrow < nvalid){
        int grow = row0 + lrow;
        float scale = (MODE==1) ? w_of[grow] : 0.f;
        #pragma unroll
        for (int j=0;j<4;j++){
          int col = col0 + wc + j*16 + fr;
          float v = acc[i][j][r] + bias_v[j];
          if (MODE==0){
            // gelu, tanh form: v - v/(e^{2u}+1), u = 0.79788456(v + 0.044715 v^3)
            float u = v*(0.7978845608f + 0.0356774081f*v*v);
            float z = __expf(2.f*u);
            v = v - __fdividef(v, z + 1.f);
          } else {
            v *= scale;
          }
          Out[(size_t)grow*N + col] = f2bf(v);
        }
      }
    }
  }
}

// ---- combine: out[t] = y[slot0] + y[slot1]; 2 tokens per block ----
__global__ __launch_bounds__(256) void combine_kernel(
    const unsigned short* __restrict__ y, const int* __restrict__ slot_of,
    float* __restrict__ out)
{
  #pragma unroll
  for (int s=0; s<2; ++s){
    int tok = blockIdx.x*2 + s;
    int s0 = slot_of[tok*2], s1 = slot_of[tok*2+1];
    const ushort4* y0 = (const ushort4*)(y + (size_t)s0*H_DIM);
    const ushort4* y1 = (const ushort4*)(y + (size_t)s1*H_DIM);
    float4* o = (float4*)(out + (size_t)tok*H_DIM);
    ushort4 a = y0[threadIdx.x], b = y1[threadIdx.x];
    float4 r;
    r.x = bf2f(a.x)+bf2f(b.x);
    r.y = bf2f(a.y)+bf2f(b.y);
    r.z = bf2f(a.z)+bf2f(b.z);
    r.w = bf2f(a.w)+bf2f(b.w);
    o[threadIdx.x] = r;
  }
}

extern "C" void kernel_launch(void* const* d_in, const int* in_sizes, int n_in,
                              void* d_out, int out_size, void* d_ws, size_t ws_size,
                              hipStream_t stream) {
  const float* x  = (const float*)d_in[0];
  const float* Wg = (const float*)d_in[1];
  const float* bg = (const float*)d_in[2];
  const float* W1 = (const float*)d_in[3];
  const float* b1 = (const float*)d_in[4];
  const float* W2 = (const float*)d_in[5];
  const float* b2 = (const float*)d_in[6];
  float* out = (float*)d_out;
  char* ws = (char*)d_ws;

  int*   cnt      = (int*)  (ws + OFF_CNT);
  int*   idxp     = (int*)  (ws + OFF_IDX);
  int*   posp     = (int*)  (ws + OFF_POS);
  float* wvp      = (float*)(ws + OFF_WV);
  int*   slot_of  = (int*)  (ws + OFF_SLOT);
  float* w_of     = (float*)(ws + OFF_WOF);
  unsigned short* Xg  = (unsigned short*)(ws + OFF_XG);
  unsigned short* W1t = (unsigned short*)(ws + OFF_W1T);
  unsigned short* W2t = (unsigned short*)(ws + OFF_W2T);
  unsigned short* mid = (unsigned short*)(ws + OFF_MID);
  unsigned short* y   = (unsigned short*)(ws + OFF_Y);

  hipMemsetAsync(ws + OFF_CNT, 0, 32, stream);

  // prep: gate (256) + W1 strip-transconv (1024)
  prep_kernel<<<dim3(1280), 256, 0, stream>>>(
      W1, W1t, x, Wg, bg, cnt, idxp, posp, wvp);
  route_gather_kernel<<<SLOTS/8, 256, 0, stream>>>(x, idxp, posp, wvp, cnt, Xg, w_of, slot_of);

  // GEMM1 launch: 1024 W2 strip-transconv blocks + 2304 GEMM blocks
  gemm128_kernel<0><<<dim3(1024 + 2304), 256, 0, stream>>>(
      Xg, W1t, b1, mid, cnt, nullptr, W2, W2t, FF_DIM, H_DIM, 3);
  // GEMM2: 18 tile-bands x 2 col-bands = 36 chunks -> 5 rounds x 128 = 640
  gemm128_kernel<1><<<dim3(640), 256, 0, stream>>>(
      mid, W2t, b2, y, cnt, w_of, nullptr, nullptr, H_DIM, FF_DIM, 1);

  combine_kernel<<<T_TOK/2, 256, 0, stream>>>(y, slot_of, out);
}